// Round 3
// baseline (455.748 us; speedup 1.0000x reference)
//
#include <hip/hip_runtime.h>

#define T_SEQ 8192
#define NH 16
#define HD 64
#define DIM 1024
#define ROWS 16384   // 2*8192
#define CHK 256
#define NCHK 32

typedef float f32x4 __attribute__((ext_vector_type(4)));
typedef __bf16 bf16x8 __attribute__((ext_vector_type(8)));
typedef short short8 __attribute__((ext_vector_type(8)));
typedef short short4v __attribute__((ext_vector_type(4)));
typedef unsigned short ushort_t;

__device__ __forceinline__ float bf2f(ushort_t u){ return __uint_as_float(((unsigned)u)<<16); }
__device__ __forceinline__ ushort_t f2bf(float f){
  unsigned u = __float_as_uint(f);
  u += 0x7FFFu + ((u>>16)&1u);
  return (ushort_t)(u>>16);
}
#define BFLO(u) __uint_as_float((u)<<16)
#define BFHI(u) __uint_as_float((u)&0xFFFF0000u)
#define MFMA16(a,b,c) __builtin_amdgcn_mfma_f32_16x16x32_bf16((a),(b),(c),0,0,0)

__device__ __forceinline__ void gload16(const void* g, void* l){
  __builtin_amdgcn_global_load_lds(
      (const __attribute__((address_space(1))) void*)g,
      (__attribute__((address_space(3))) void*)l, 16, 0, 0);
}

// ---------------- transpose 5 weights 1024x1024 fp32 -> bf16 (N-major) ----------------
__global__ __launch_bounds__(256) void transpose_all(const float* __restrict__ Wq,
    const float* __restrict__ Wk, const float* __restrict__ Wv,
    const float* __restrict__ Wg, const float* __restrict__ Wo,
    ushort_t* __restrict__ wcat, ushort_t* __restrict__ wot){
  int z = blockIdx.z;
  const float* W = (z==0)?Wq:(z==1)?Wk:(z==2)?Wv:(z==3)?Wg:Wo;
  ushort_t* D = (z<4)? (wcat + (size_t)z*DIM*DIM) : wot;
  __shared__ float tile[64][65];
  int k0 = blockIdx.x*64, n0 = blockIdx.y*64;
  int tid = threadIdx.x;
  #pragma unroll
  for (int it=0; it<16; ++it){
    int idx = tid + it*256;
    int r = idx>>6, c = idx&63;
    tile[r][c] = W[(size_t)(k0+r)*DIM + n0+c];
  }
  __syncthreads();
  #pragma unroll
  for (int it=0; it<16; ++it){
    int idx = tid + it*256;
    int r = idx>>6, c = idx&63;
    D[(size_t)(n0+r)*DIM + k0+c] = f2bf(tile[c][r]);
  }
}

// ---------------- 256x256 deep-pipelined MFMA GEMM: C = A[M,1024] * Bt[N,1024]^T ----------------
// BK=32, double-buffered 64KB LDS, global_load_lds staging, 8 waves (2Mx4N),
// per-wave 128x64 output, XCD-swizzled blocks, setprio around MFMA clusters.
template<int OUT_BF16>
__global__ __launch_bounds__(512,2) void gemm256(const ushort_t* __restrict__ A,
    const ushort_t* __restrict__ Bt, void* __restrict__ Cv, int N){
  __shared__ __align__(16) ushort_t As[2*256*32];
  __shared__ __align__(16) ushort_t Bs[2*256*32];
  int tid = threadIdx.x, lane = tid&63, w = tid>>6;
  int wr = w>>2, wc = w&3;
  // bijective XCD swizzle (gridDim.x % 8 == 0 for both GEMMs)
  int nwg = gridDim.x, bid = blockIdx.x;
  int wg = (bid&7)*(nwg>>3) + (bid>>3);
  int mb = wg & 63, nb = wg >> 6;       // gx = M/256 = 64 always
  int m0 = mb<<8, n0 = nb<<8;
  // staging pointers: 16 issues/tile/matrix, wave w does j=2w,2w+1; 16 rows per issue
  const ushort_t* srcA[2]; const ushort_t* srcB[2];
  #pragma unroll
  for (int i=0;i<2;++i){
    int j = w*2 + i;
    int r = j*16 + (lane>>2);
    srcA[i] = &A [(size_t)(m0 + r)*1024 + (lane&3)*8];
    srcB[i] = &Bt[(size_t)(n0 + r)*1024 + (lane&3)*8];
  }
  int dj = w*1024;                      // dest elem offset of issue j=2w
  f32x4 acc[8][4] = {};
  // prologue: stage tile 0 into buf 0
  gload16(srcA[0], &As[dj]);
  gload16(srcA[1], &As[dj+512]);
  gload16(srcB[0], &Bs[dj]);
  gload16(srcB[1], &Bs[dj+512]);
  asm volatile("s_waitcnt vmcnt(0)" ::: "memory");
  __builtin_amdgcn_s_barrier();

  int aoff = (wr*128 + (lane&15))*32 + (lane>>4)*8;
  int boff = (wc*64  + (lane&15))*32 + (lane>>4)*8;
  const int NT = 32;                    // K=1024 / BK=32
  for (int t=0; t<NT; ++t){
    int db = t&1;
    const ushort_t* as = &As[db*8192];
    const ushort_t* bs = &Bs[db*8192];
    // front-loaded staging of tile t+1 into the other buffer
    if (t+1 < NT){
      int xb = (db^1)*8192;
      gload16(srcA[0] + (t+1)*32, &As[xb + dj]);
      gload16(srcA[1] + (t+1)*32, &As[xb + dj + 512]);
      gload16(srcB[0] + (t+1)*32, &Bs[xb + dj]);
      gload16(srcB[1] + (t+1)*32, &Bs[xb + dj + 512]);
    }
    // phase 0: fragments for m0..3, all n
    bf16x8 bfr[4], af[4];
    #pragma unroll
    for (int n=0;n<4;++n) bfr[n] = *(const bf16x8*)&bs[boff + n*512];
    #pragma unroll
    for (int m=0;m<4;++m) af[m] = *(const bf16x8*)&as[aoff + m*512];
    __builtin_amdgcn_s_barrier();
    __builtin_amdgcn_s_setprio(1);
    #pragma unroll
    for (int m=0;m<4;++m)
      #pragma unroll
      for (int n=0;n<4;++n)
        acc[m][n] = MFMA16(af[m], bfr[n], acc[m][n]);
    __builtin_amdgcn_s_setprio(0);
    __builtin_amdgcn_s_barrier();
    // phase 1: fragments for m4..7
    bf16x8 af2[4];
    #pragma unroll
    for (int m=0;m<4;++m) af2[m] = *(const bf16x8*)&as[aoff + (m+4)*512];
    __builtin_amdgcn_s_setprio(1);
    #pragma unroll
    for (int m=0;m<4;++m)
      #pragma unroll
      for (int n=0;n<4;++n)
        acc[m+4][n] = MFMA16(af2[m], bfr[n], acc[m+4][n]);
    __builtin_amdgcn_s_setprio(0);
    asm volatile("s_waitcnt vmcnt(0)" ::: "memory");   // drain t+1 staging (issued 2 phases ago)
    __builtin_amdgcn_s_barrier();
  }
  // epilogue
  #pragma unroll
  for (int m=0;m<8;++m){
    int row = m0 + wr*128 + m*16 + (lane>>4)*4;
    #pragma unroll
    for (int n=0;n<4;++n){
      int col = n0 + wc*64 + n*16 + (lane&15);
      #pragma unroll
      for (int r=0;r<4;++r){
        float v = acc[m][n][r];
        if (OUT_BF16) ((ushort_t*)Cv)[(size_t)(row+r)*N + col] = f2bf(v);
        else          ((float*)Cv)[(size_t)(row+r)*N + col] = v;
      }
    }
  }
}

// ---------------- rmsnorm of q,k,v rows (in place, bf16) ----------------
__global__ __launch_bounds__(256) void rmsnorm_qkv(ushort_t* __restrict__ qkvg){
  int row = blockIdx.x; int tid = threadIdx.x;
  size_t base = (size_t)row*4096;
  __shared__ float red[4];
  int lane = tid&63, w = tid>>6;
  for (int mat=0; mat<3; ++mat){
    ushort_t* pp = &qkvg[base + mat*1024 + tid*4];
    short4v sv = *(const short4v*)pp;
    float v0 = bf2f((ushort_t)sv[0]), v1 = bf2f((ushort_t)sv[1]);
    float v2 = bf2f((ushort_t)sv[2]), v3 = bf2f((ushort_t)sv[3]);
    float ss = v0*v0+v1*v1+v2*v2+v3*v3;
    #pragma unroll
    for (int off=32; off>=1; off>>=1) ss += __shfl_xor(ss, off);
    if (lane==0) red[w] = ss;
    __syncthreads();
    float tot = red[0]+red[1]+red[2]+red[3];
    float rms = rsqrtf(tot*(1.f/1024.f)+1e-6f);
    short4v ov;
    ov[0]=(short)f2bf(v0*rms); ov[1]=(short)f2bf(v1*rms);
    ov[2]=(short)f2bf(v2*rms); ov[3]=(short)f2bf(v3*rms);
    *(short4v*)pp = ov;
    __syncthreads();
  }
}

// ---------------- gt = logsigmoid(x @ Wgt)/16  +  fused x->bf16 cast ----------------
__global__ __launch_bounds__(256) void gt_ker(const float* __restrict__ x,
    const float* __restrict__ Wgt, float* __restrict__ gtb, ushort_t* __restrict__ xbf){
  int row = blockIdx.x; int b = row>>13; int t = row & (T_SEQ-1);
  int tid = threadIdx.x; int lane = tid&63; int w = tid>>6;
  __shared__ float xs[1024];
  #pragma unroll
  for (int i=0;i<4;++i) xs[tid+256*i] = x[(size_t)row*DIM + tid+256*i];
  __syncthreads();
  // fused cast
  short4v xb4;
  #pragma unroll
  for (int k2=0;k2<4;++k2) xb4[k2] = (short)f2bf(xs[tid*4+k2]);
  *(short4v*)&xbf[(size_t)row*DIM + tid*4] = xb4;
  // gt dot products
  float a0=0,a1=0,a2=0,a3=0;
  #pragma unroll
  for (int jj=0;jj<16;++jj){
    int j = lane + 64*jj;
    float xv = xs[j];
    const float* wp = &Wgt[(size_t)j*NH + w*4];
    a0 += xv*wp[0]; a1 += xv*wp[1]; a2 += xv*wp[2]; a3 += xv*wp[3];
  }
  #pragma unroll
  for (int off=32; off>=1; off>>=1){
    a0 += __shfl_xor(a0, off); a1 += __shfl_xor(a1, off);
    a2 += __shfl_xor(a2, off); a3 += __shfl_xor(a3, off);
  }
  if (lane==0){
    float za[4] = {a0,a1,a2,a3};
    #pragma unroll
    for (int i=0;i<4;++i){
      float z = za[i];
      float ls = fminf(z,0.f) - log1pf(__expf(-fabsf(z)));
      gtb[((size_t)(b*NH + w*4 + i))*T_SEQ + t] = ls * (1.f/16.f);
    }
  }
}

// ---------------- attention phase 1 (MFMA): kv = kd^T v  (kv stored transposed [e][d]) ----------------
__global__ __launch_bounds__(256,2) void attn_p1(const ushort_t* __restrict__ qkvg,
    const float* __restrict__ gtb, float* __restrict__ Bb, float* __restrict__ kvb){
  __shared__ __align__(16) ushort_t sh2[32768];   // 64 KB: kdT [64][256] | vT [64][256], swizzled
  ushort_t* kdt = sh2;
  ushort_t* vt  = sh2 + 16384;
  float* tmp = (float*)sh2;
  int bid = blockIdx.x; int n = bid&31; int bh = bid>>5; int b = bh>>4; int h = bh&15;
  int t0 = n*CHK; int tid = threadIdx.x; int lane = tid&63; int w = tid>>6;
  float vscan = gtb[(size_t)bh*T_SEQ + t0 + tid];
  #pragma unroll
  for (int off=1; off<64; off<<=1){ float u = __shfl_up(vscan, off); if (lane>=off) vscan += u; }
  if (lane==63) tmp[w] = vscan;
  __syncthreads();
  float pre=0;
  #pragma unroll
  for (int i=0;i<4;++i) if (i<w) pre += tmp[i];
  float bc = vscan + pre;
  float Bn = tmp[0]+tmp[1]+tmp[2]+tmp[3];
  if (tid==0) Bb[bid] = Bn;
  __syncthreads();
  {
    int j = tid;
    size_t rowb = ((size_t)(b*T_SEQ + t0 + j))*4096;
    float sj = __expf(Bn - bc);
    #pragma unroll
    for (int q8=0; q8<8; ++q8){
      short8 k8 = *(const short8*)&qkvg[rowb + 1024 + h*HD + q8*8];
      short8 v8 = *(const short8*)&qkvg[rowb + 2048 + h*HD + q8*8];
      #pragma unroll
      for (int kk=0; kk<8; ++kk){
        int d = q8*8 + kk;
        kdt[(d<<8) + (((j>>3)^(d&7))<<3) + (j&7)] = f2bf(bf2f((ushort_t)k8[kk])*sj);
        vt [(d<<8) + (((j>>3)^(d&7))<<3) + (j&7)] = (ushort_t)v8[kk];
      }
    }
  }
  __syncthreads();
  f32x4 acc[4] = {};
  #pragma unroll
  for (int s=0; s<8; ++s){
    int d = w*16 + (lane&15);
    int jj = s*32 + (lane>>4)*8;
    bf16x8 ka = *(const bf16x8*)&kdt[(d<<8) + (((jj>>3)^(d&7))<<3)];
    #pragma unroll
    for (int et=0; et<4; ++et){
      int e = et*16 + (lane&15);
      bf16x8 vf = *(const bf16x8*)&vt[(e<<8) + (((jj>>3)^(e&7))<<3)];
      acc[et] = MFMA16(ka, vf, acc[et]);
    }
  }
  float* kvp = &kvb[(size_t)bid*4096];
  #pragma unroll
  for (int et=0; et<4; ++et)
    #pragma unroll
    for (int r=0; r<4; ++r)
      kvp[(et*16 + (lane&15))*64 + w*16 + (lane>>4)*4 + r] = acc[et][r];
}

// ---------------- state scan: one thread per (bh, e*64+d), coalesced ----------------
__global__ __launch_bounds__(256) void scan_ker(const float* __restrict__ kvb,
    const float* __restrict__ Bb, ushort_t* __restrict__ Sb){
  int gidx = blockIdx.x*256 + threadIdx.x;   // 32*4096 total
  int bh = gidx >> 12; int f = gidx & 4095;
  float S = 0.f;
  const float* kp = &kvb[(size_t)bh*NCHK*4096 + f];
  ushort_t* sp = &Sb[(size_t)bh*NCHK*4096 + f];
  for (int n=0;n<NCHK;++n){
    sp[(size_t)n*4096] = f2bf(S);            // state BEFORE chunk n, layout [e][d]
    S = __expf(Bb[bh*NCHK+n])*S + kp[(size_t)n*4096];
  }
}

// ---------------- attention phase 3 (MFMA): intra + cross + rmsnorm + silu ----------------
__global__ __launch_bounds__(512,2) void attn_p3(const ushort_t* __restrict__ qkvg,
    const float* __restrict__ gtb, const ushort_t* __restrict__ Sb,
    ushort_t* __restrict__ oact){
  __shared__ __align__(16) ushort_t sh[(32768+16384+1024+32)/2];
  ushort_t* vt = sh;                     // [e=64][j=256] swizzled
  ushort_t* ps = sh + 16384;             // per-wave [32][32] swizzled
  float* bcs = (float*)(sh + 24576);
  float* tmp = (float*)(sh + 25088);
  int bid = blockIdx.x; int n = bid&31; int bh = bid>>5; int b = bh>>4; int h = bh&15;
  int t0 = n*CHK; int tid = threadIdx.x; int lane = tid&63; int w = tid>>6;
  float vscan = 0.f;
  if (tid < 256){
    vscan = gtb[(size_t)bh*T_SEQ + t0 + tid];
    #pragma unroll
    for (int off=1; off<64; off<<=1){ float u = __shfl_up(vscan, off); if (lane>=off) vscan += u; }
    if (lane==63) tmp[w] = vscan;
  }
  __syncthreads();
  if (tid < 256){
    float pre=0;
    #pragma unroll
    for (int i=0;i<4;++i) if (i<w) pre += tmp[i];
    bcs[tid] = vscan + pre;
  }
  {
    int j = tid>>1, ehalf = tid&1;
    size_t rowb = ((size_t)(b*T_SEQ + t0 + j))*4096;
    #pragma unroll
    for (int q8=0; q8<4; ++q8){
      short8 v8 = *(const short8*)&qkvg[rowb + 2048 + h*HD + ehalf*32 + q8*8];
      #pragma unroll
      for (int kk=0; kk<8; ++kk){
        int e = ehalf*32 + q8*8 + kk;
        vt[(e<<8) + (((j>>3)^(e&7))<<3) + (j&7)] = (ushort_t)v8[kk];
      }
    }
  }
  __syncthreads();
  int wrow = w*32;
  size_t chunkbase = (size_t)b*T_SEQ + t0;
  bf16x8 qf[2][2];
  #pragma unroll
  for (int rt=0; rt<2; ++rt)
    #pragma unroll
    for (int s=0; s<2; ++s)
      qf[rt][s] = *(const bf16x8*)&qkvg[(chunkbase + wrow + rt*16 + (lane&15))*4096
                                        + h*HD + s*32 + (lane>>4)*8];
  f32x4 o_[2][4] = {};
  #pragma unroll
  for (int s=0; s<2; ++s)
    #pragma unroll
    for (int et=0; et<4; ++et){
      bf16x8 stf = *(const bf16x8*)&Sb[(size_t)bid*4096 + (et*16 + (lane&15))*64
                                       + s*32 + (lane>>4)*8];
      #pragma unroll
      for (int rt=0; rt<2; ++rt)
        o_[rt][et] = MFMA16(qf[rt][s], stf, o_[rt][et]);
    }
  #pragma unroll
  for (int rt=0; rt<2; ++rt)
    #pragma unroll
    for (int rr=0; rr<4; ++rr){
      float fs = 0.125f*__expf(bcs[wrow + rt*16 + (lane>>4)*4 + rr]);
      #pragma unroll
      for (int et=0; et<4; ++et) o_[rt][et][rr] *= fs;
    }
  for (int hb=0; hb<=w; ++hb){
    int jb = hb>>1, ch = hb&1;
    int jbase = jb*64 + ch*32;
    float mb = bcs[jb*64];
    float r8[2][4];
    #pragma unroll
    for (int rt=0; rt<2; ++rt)
      #pragma unroll
      for (int rr=0; rr<4; ++rr)
        r8[rt][rr] = 0.125f*__expf(bcs[wrow + rt*16 + (lane>>4)*4 + rr] - mb);
    float c2[2];
    #pragma unroll
    for (int ct=0; ct<2; ++ct)
      c2[ct] = __expf(mb - bcs[jbase + ct*16 + (lane&15)]);
    f32x4 s2[2][2] = {};
    #pragma unroll
    for (int s=0; s<2; ++s)
      #pragma unroll
      for (int ct=0; ct<2; ++ct){
        bf16x8 kf = *(const bf16x8*)&qkvg[(chunkbase + jbase + ct*16 + (lane&15))*4096
                                          + 1024 + h*HD + s*32 + (lane>>4)*8];
        #pragma unroll
        for (int rt=0; rt<2; ++rt)
          s2[rt][ct] = MFMA16(qf[rt][s], kf, s2[rt][ct]);
      }
    bool dia = (hb == w);
    #pragma unroll
    for (int rt=0; rt<2; ++rt)
      #pragma unroll
      for (int ct=0; ct<2; ++ct)
        #pragma unroll
        for (int rr=0; rr<4; ++rr){
          int pi = rt*16 + (lane>>4)*4 + rr;
          int pj = ct*16 + (lane&15);
          float pv = s2[rt][ct][rr] * r8[rt][rr] * c2[ct];
          if (dia && (jbase + pj) > (wrow + pi)) pv = 0.f;
          ps[w*1024 + pi*32 + (((pj>>3) ^ ((pi>>2)&3))<<3) + (pj&7)] = f2bf(pv);
        }
    bf16x8 vf[4];
    #pragma unroll
    for (int et=0; et<4; ++et){
      int e = et*16 + (lane&15);
      int jj = jbase + (lane>>4)*8;
      vf[et] = *(const bf16x8*)&vt[(e<<8) + (((jj>>3) ^ (e&7))<<3)];
    }
    bf16x8 pf[2];
    #pragma unroll
    for (int rt=0; rt<2; ++rt){
      int i = rt*16 + (lane&15);
      pf[rt] = *(const bf16x8*)&ps[w*1024 + i*32 + (((lane>>4) ^ ((i>>2)&3))<<3)];
    }
    #pragma unroll
    for (int rt=0; rt<2; ++rt)
      #pragma unroll
      for (int et=0; et<4; ++et)
        o_[rt][et] = MFMA16(pf[rt], vf[et], o_[rt][et]);
  }
  float rms8[2][4];
  #pragma unroll
  for (int rt=0; rt<2; ++rt)
    #pragma unroll
    for (int rr=0; rr<4; ++rr){
      float ssq = 0.f;
      #pragma unroll
      for (int et=0; et<4; ++et){ float xx = o_[rt][et][rr]; ssq += xx*xx; }
      ssq += __shfl_xor(ssq,1); ssq += __shfl_xor(ssq,2);
      ssq += __shfl_xor(ssq,4); ssq += __shfl_xor(ssq,8);
      rms8[rt][rr] = rsqrtf(ssq*(1.f/64.f)+1e-6f);
    }
  #pragma unroll
  for (int eh=0; eh<2; ++eh){
    #pragma unroll
    for (int rt=0; rt<2; ++rt)
      #pragma unroll
      for (int e2=0; e2<2; ++e2){
        int et = eh*2 + e2;
        #pragma unroll
        for (int rr=0; rr<4; ++rr){
          int pi = rt*16 + (lane>>4)*4 + rr;
          int pj = e2*16 + (lane&15);
          ps[w*1024 + pi*32 + (((pj>>3) ^ ((pi>>2)&3))<<3) + (pj&7)] =
            f2bf(o_[rt][et][rr]*rms8[rt][rr]);
        }
      }
    int i2 = lane&31, e16 = (lane>>5)*16;
    int gr0 = e16>>3;
    int f = (i2>>2)&3;
    short8 ov0 = *(const short8*)&ps[w*1024 + i2*32 + ((gr0^f)<<3)];
    short8 ov1 = *(const short8*)&ps[w*1024 + i2*32 + (((gr0+1)^f)<<3)];
    size_t rowg = chunkbase + wrow + i2;
    short8 gv0 = *(const short8*)&qkvg[rowg*4096 + 3072 + h*HD + eh*32 + e16];
    short8 gv1 = *(const short8*)&qkvg[rowg*4096 + 3072 + h*HD + eh*32 + e16 + 8];
    ushort_t outv[16];
    #pragma unroll
    for (int k=0;k<8;++k){
      float gf = bf2f((ushort_t)gv0[k]);
      float sg = gf/(1.f+__expf(-gf));
      outv[k] = f2bf(bf2f((ushort_t)ov0[k])*sg);
    }
    #pragma unroll
    for (int k=0;k<8;++k){
      float gf = bf2f((ushort_t)gv1[k]);
      float sg = gf/(1.f+__expf(-gf));
      outv[8+k] = f2bf(bf2f((ushort_t)ov1[k])*sg);
    }
    ushort_t* op = &oact[rowg*DIM + h*HD + eh*32 + e16];
    *(short8*)&op[0] = *(short8*)&outv[0];
    *(short8*)&op[8] = *(short8*)&outv[8];
  }
}

// ---------------- launch ----------------
extern "C" void kernel_launch(void* const* d_in, const int* in_sizes, int n_in,
                              void* d_out, int out_size, void* d_ws, size_t ws_size,
                              hipStream_t stream){
  const float* x  = (const float*)d_in[0];
  const float* Wq = (const float*)d_in[1];
  const float* Wk = (const float*)d_in[2];
  const float* Wv = (const float*)d_in[3];
  const float* Wg = (const float*)d_in[4];
  const float* Wgt= (const float*)d_in[5];
  const float* Wo = (const float*)d_in[6];
  float* out = (float*)d_out;

  char* p = (char*)d_ws;
  ushort_t* xbf  = (ushort_t*)p; p += (size_t)ROWS*DIM*2;
  ushort_t* wcat = (ushort_t*)p; p += (size_t)4*DIM*DIM*2;
  ushort_t* wot  = (ushort_t*)p; p += (size_t)DIM*DIM*2;
  ushort_t* qkvg = (ushort_t*)p; p += (size_t)ROWS*4096*2;
  float* gtb = (float*)p; p += (size_t)32*T_SEQ*4;
  float* Bb  = (float*)p; p += 1024*4;
  float* kvb = (float*)p; p += (size_t)1024*4096*4;
  ushort_t* Sb = (ushort_t*)p; p += (size_t)1024*4096*2;
  ushort_t* oact = (ushort_t*)p; p += (size_t)ROWS*DIM*2;
  if ((size_t)(p - (char*)d_ws) > ws_size) return;

  gt_ker<<<ROWS,256,0,stream>>>(x, Wgt, gtb, xbf);
  transpose_all<<<dim3(16,16,5),256,0,stream>>>(Wq, Wk, Wv, Wg, Wo, wcat, wot);
  gemm256<1><<<dim3(64*16), 512, 0, stream>>>(xbf, wcat, qkvg, 4096);
  rmsnorm_qkv<<<ROWS,256,0,stream>>>(qkvg);
  attn_p1<<<1024,256,0,stream>>>(qkvg, gtb, Bb, kvb);
  scan_ker<<<512,256,0,stream>>>(kvb, Bb, Sb);
  attn_p3<<<1024,512,0,stream>>>(qkvg, gtb, Sb, oact);
  gemm256<0><<<dim3(64*4), 512, 0, stream>>>(oact, wot, out, 1024);
}

// Round 4
// 433.375 us; speedup vs baseline: 1.0516x; 1.0516x over previous
//
#include <hip/hip_runtime.h>

#define T_SEQ 8192
#define NH 16
#define HD 64
#define DIM 1024
#define ROWS 16384   // 2*8192
#define CHK 256
#define NCHK 32

typedef float f32x4 __attribute__((ext_vector_type(4)));
typedef __bf16 bf16x8 __attribute__((ext_vector_type(8)));
typedef short short8 __attribute__((ext_vector_type(8)));
typedef short short4v __attribute__((ext_vector_type(4)));
typedef unsigned short ushort_t;

__device__ __forceinline__ float bf2f(ushort_t u){ return __uint_as_float(((unsigned)u)<<16); }
__device__ __forceinline__ ushort_t f2bf(float f){
  unsigned u = __float_as_uint(f);
  u += 0x7FFFu + ((u>>16)&1u);
  return (ushort_t)(u>>16);
}
#define BFLO(u) __uint_as_float((u)<<16)
#define BFHI(u) __uint_as_float((u)&0xFFFF0000u)
#define MFMA16(a,b,c) __builtin_amdgcn_mfma_f32_16x16x32_bf16((a),(b),(c),0,0,0)

__device__ __forceinline__ void gload16(const void* g, void* l){
  __builtin_amdgcn_global_load_lds(
      (const __attribute__((address_space(1))) void*)g,
      (__attribute__((address_space(3))) void*)l, 16, 0, 0);
}

// ---------------- transpose 5 weights 1024x1024 fp32 -> bf16 (N-major) ----------------
__global__ __launch_bounds__(256) void transpose_all(const float* __restrict__ Wq,
    const float* __restrict__ Wk, const float* __restrict__ Wv,
    const float* __restrict__ Wg, const float* __restrict__ Wo,
    ushort_t* __restrict__ wcat, ushort_t* __restrict__ wot){
  int z = blockIdx.z;
  const float* W = (z==0)?Wq:(z==1)?Wk:(z==2)?Wv:(z==3)?Wg:Wo;
  ushort_t* D = (z<4)? (wcat + (size_t)z*DIM*DIM) : wot;
  __shared__ float tile[64][65];
  int k0 = blockIdx.x*64, n0 = blockIdx.y*64;
  int tid = threadIdx.x;
  #pragma unroll
  for (int it=0; it<16; ++it){
    int idx = tid + it*256;
    int r = idx>>6, c = idx&63;
    tile[r][c] = W[(size_t)(k0+r)*DIM + n0+c];
  }
  __syncthreads();
  #pragma unroll
  for (int it=0; it<16; ++it){
    int idx = tid + it*256;
    int r = idx>>6, c = idx&63;
    D[(size_t)(n0+r)*DIM + k0+c] = f2bf(tile[c][r]);
  }
}

// ---------------- 256x256 MFMA GEMM, BK=64, dbuf 128KB LDS, swizzled gload_lds ----------------
// 8 waves (2Mx4N), per-wave 128x64 out. LDS rows are 128B (full bank wrap);
// granule swizzle slot = g ^ (row&7) applied on the GLOBAL source (linear LDS dest,
// rule both-sides-or-neither) and on ds_read. R2-proven conflict-free read pattern.
template<int OUT_BF16>
__global__ __launch_bounds__(512,2) void gemm256(const ushort_t* __restrict__ A,
    const ushort_t* __restrict__ Bt, void* __restrict__ Cv, int N){
  __shared__ __align__(16) ushort_t As[2*256*64];
  __shared__ __align__(16) ushort_t Bs[2*256*64];
  int tid = threadIdx.x, lane = tid&63, w = tid>>6;
  int wr = w>>2, wc = w&3;
  int nwg = gridDim.x, bid = blockIdx.x;
  int wg = (bid&7)*(nwg>>3) + (bid>>3);          // bijective XCD swizzle (nwg%8==0)
  int mb = wg & 63, nb = wg >> 6;                // M/256 == 64 for both GEMMs
  int m0 = mb<<8, n0 = nb<<8;
  // staging: wave w covers rows w*32..w*32+31 (4 issues of 8 rows); lane L writes
  // LDS slot L&7 of row +L>>3, so its global granule is (L&7)^(L>>3).
  const ushort_t* srcA = &A [(size_t)(m0 + w*32 + (lane>>3))*1024 + (((lane&7)^(lane>>3))<<3)];
  const ushort_t* srcB = &Bt[(size_t)(n0 + w*32 + (lane>>3))*1024 + (((lane&7)^(lane>>3))<<3)];
  int dstw = w*2048;
  f32x4 acc[8][4] = {};
  // prologue: stage K-tile 0 into buf0
  #pragma unroll
  for (int q=0;q<4;++q) gload16(srcA + q*8192, &As[dstw + q*512]);
  #pragma unroll
  for (int q=0;q<4;++q) gload16(srcB + q*8192, &Bs[dstw + q*512]);
  asm volatile("s_waitcnt vmcnt(0)" ::: "memory");
  __builtin_amdgcn_s_barrier();

  const int NT = 16;                              // K=1024 / BK=64
  for (int t=0; t<NT; ++t){
    int db = t&1;
    const ushort_t* as = &As[db*16384];
    const ushort_t* bs = &Bs[db*16384];
    // front-loaded staging of K-tile t+1 into the other buffer
    if (t+1 < NT){
      int xb = (db^1)*16384;
      #pragma unroll
      for (int q=0;q<4;++q) gload16(srcA + q*8192 + (t+1)*64, &As[xb + dstw + q*512]);
      #pragma unroll
      for (int q=0;q<4;++q) gload16(srcB + q*8192 + (t+1)*64, &Bs[xb + dstw + q*512]);
    }
    // B fragments for the whole K-tile (reused by all 4 phases)
    bf16x8 bfr[4][2];
    #pragma unroll
    for (int ni=0;ni<4;++ni){
      int row = wc*64 + ni*16 + (lane&15);
      #pragma unroll
      for (int kk=0;kk<2;++kk){
        int g = kk*4 + (lane>>4);
        bfr[ni][kk] = *(const bf16x8*)&bs[row*64 + ((g^(row&7))<<3)];
      }
    }
    // 4 phases x 16 MFMA (C-quadrants), setprio around MFMA clusters
    #pragma unroll
    for (int p=0;p<4;++p){
      bf16x8 af[2][2];
      #pragma unroll
      for (int mi2=0;mi2<2;++mi2){
        int row = wr*128 + (p*2+mi2)*16 + (lane&15);
        #pragma unroll
        for (int kk=0;kk<2;++kk){
          int g = kk*4 + (lane>>4);
          af[mi2][kk] = *(const bf16x8*)&as[row*64 + ((g^(row&7))<<3)];
        }
      }
      __builtin_amdgcn_s_barrier();
      __builtin_amdgcn_s_setprio(1);
      #pragma unroll
      for (int mi2=0;mi2<2;++mi2)
        #pragma unroll
        for (int ni=0;ni<4;++ni)
          #pragma unroll
          for (int kk=0;kk<2;++kk)
            acc[p*2+mi2][ni] = MFMA16(af[mi2][kk], bfr[ni][kk], acc[p*2+mi2][ni]);
      __builtin_amdgcn_s_setprio(0);
    }
    asm volatile("s_waitcnt vmcnt(0)" ::: "memory");  // t+1 staging landed (issued 64 MFMA ago)
    __builtin_amdgcn_s_barrier();
  }
  // epilogue
  #pragma unroll
  for (int m=0;m<8;++m){
    int row = m0 + wr*128 + m*16 + (lane>>4)*4;
    #pragma unroll
    for (int n=0;n<4;++n){
      int col = n0 + wc*64 + n*16 + (lane&15);
      #pragma unroll
      for (int r=0;r<4;++r){
        float v = acc[m][n][r];
        if (OUT_BF16) ((ushort_t*)Cv)[(size_t)(row+r)*N + col] = f2bf(v);
        else          ((float*)Cv)[(size_t)(row+r)*N + col] = v;
      }
    }
  }
}

// ---------------- rmsnorm of q,k,v rows (in place, bf16) ----------------
__global__ __launch_bounds__(256) void rmsnorm_qkv(ushort_t* __restrict__ qkvg){
  int row = blockIdx.x; int tid = threadIdx.x;
  size_t base = (size_t)row*4096;
  __shared__ float red[4];
  int lane = tid&63, w = tid>>6;
  for (int mat=0; mat<3; ++mat){
    ushort_t* pp = &qkvg[base + mat*1024 + tid*4];
    short4v sv = *(const short4v*)pp;
    float v0 = bf2f((ushort_t)sv[0]), v1 = bf2f((ushort_t)sv[1]);
    float v2 = bf2f((ushort_t)sv[2]), v3 = bf2f((ushort_t)sv[3]);
    float ss = v0*v0+v1*v1+v2*v2+v3*v3;
    #pragma unroll
    for (int off=32; off>=1; off>>=1) ss += __shfl_xor(ss, off);
    if (lane==0) red[w] = ss;
    __syncthreads();
    float tot = red[0]+red[1]+red[2]+red[3];
    float rms = rsqrtf(tot*(1.f/1024.f)+1e-6f);
    short4v ov;
    ov[0]=(short)f2bf(v0*rms); ov[1]=(short)f2bf(v1*rms);
    ov[2]=(short)f2bf(v2*rms); ov[3]=(short)f2bf(v3*rms);
    *(short4v*)pp = ov;
    __syncthreads();
  }
}

// ---------------- gt = logsigmoid(x @ Wgt)/16  +  fused x->bf16 cast ----------------
__global__ __launch_bounds__(256) void gt_ker(const float* __restrict__ x,
    const float* __restrict__ Wgt, float* __restrict__ gtb, ushort_t* __restrict__ xbf){
  int row = blockIdx.x; int b = row>>13; int t = row & (T_SEQ-1);
  int tid = threadIdx.x; int lane = tid&63; int w = tid>>6;
  __shared__ float xs[1024];
  #pragma unroll
  for (int i=0;i<4;++i) xs[tid+256*i] = x[(size_t)row*DIM + tid+256*i];
  __syncthreads();
  short4v xb4;
  #pragma unroll
  for (int k2=0;k2<4;++k2) xb4[k2] = (short)f2bf(xs[tid*4+k2]);
  *(short4v*)&xbf[(size_t)row*DIM + tid*4] = xb4;
  float a0=0,a1=0,a2=0,a3=0;
  #pragma unroll
  for (int jj=0;jj<16;++jj){
    int j = lane + 64*jj;
    float xv = xs[j];
    const float* wp = &Wgt[(size_t)j*NH + w*4];
    a0 += xv*wp[0]; a1 += xv*wp[1]; a2 += xv*wp[2]; a3 += xv*wp[3];
  }
  #pragma unroll
  for (int off=32; off>=1; off>>=1){
    a0 += __shfl_xor(a0, off); a1 += __shfl_xor(a1, off);
    a2 += __shfl_xor(a2, off); a3 += __shfl_xor(a3, off);
  }
  if (lane==0){
    float za[4] = {a0,a1,a2,a3};
    #pragma unroll
    for (int i=0;i<4;++i){
      float z = za[i];
      float ls = fminf(z,0.f) - log1pf(__expf(-fabsf(z)));
      gtb[((size_t)(b*NH + w*4 + i))*T_SEQ + t] = ls * (1.f/16.f);
    }
  }
}

// ---------------- attention phase 1 (MFMA): kv = kd^T v  (kv stored transposed [e][d]) ----------------
__global__ __launch_bounds__(256,2) void attn_p1(const ushort_t* __restrict__ qkvg,
    const float* __restrict__ gtb, float* __restrict__ Bb, float* __restrict__ kvb){
  __shared__ __align__(16) ushort_t sh2[32768];
  ushort_t* kdt = sh2;
  ushort_t* vt  = sh2 + 16384;
  float* tmp = (float*)sh2;
  int bid = blockIdx.x; int n = bid&31; int bh = bid>>5; int b = bh>>4; int h = bh&15;
  int t0 = n*CHK; int tid = threadIdx.x; int lane = tid&63; int w = tid>>6;
  float vscan = gtb[(size_t)bh*T_SEQ + t0 + tid];
  #pragma unroll
  for (int off=1; off<64; off<<=1){ float u = __shfl_up(vscan, off); if (lane>=off) vscan += u; }
  if (lane==63) tmp[w] = vscan;
  __syncthreads();
  float pre=0;
  #pragma unroll
  for (int i=0;i<4;++i) if (i<w) pre += tmp[i];
  float bc = vscan + pre;
  float Bn = tmp[0]+tmp[1]+tmp[2]+tmp[3];
  if (tid==0) Bb[bid] = Bn;
  __syncthreads();
  {
    int j = tid;
    size_t rowb = ((size_t)(b*T_SEQ + t0 + j))*4096;
    float sj = __expf(Bn - bc);
    #pragma unroll
    for (int q8=0; q8<8; ++q8){
      short8 k8 = *(const short8*)&qkvg[rowb + 1024 + h*HD + q8*8];
      short8 v8 = *(const short8*)&qkvg[rowb + 2048 + h*HD + q8*8];
      #pragma unroll
      for (int kk=0; kk<8; ++kk){
        int d = q8*8 + kk;
        kdt[(d<<8) + (((j>>3)^(d&7))<<3) + (j&7)] = f2bf(bf2f((ushort_t)k8[kk])*sj);
        vt [(d<<8) + (((j>>3)^(d&7))<<3) + (j&7)] = (ushort_t)v8[kk];
      }
    }
  }
  __syncthreads();
  f32x4 acc[4] = {};
  #pragma unroll
  for (int s=0; s<8; ++s){
    int d = w*16 + (lane&15);
    int jj = s*32 + (lane>>4)*8;
    bf16x8 ka = *(const bf16x8*)&kdt[(d<<8) + (((jj>>3)^(d&7))<<3)];
    #pragma unroll
    for (int et=0; et<4; ++et){
      int e = et*16 + (lane&15);
      bf16x8 vf = *(const bf16x8*)&vt[(e<<8) + (((jj>>3)^(e&7))<<3)];
      acc[et] = MFMA16(ka, vf, acc[et]);
    }
  }
  float* kvp = &kvb[(size_t)bid*4096];
  #pragma unroll
  for (int et=0; et<4; ++et)
    #pragma unroll
    for (int r=0; r<4; ++r)
      kvp[(et*16 + (lane&15))*64 + w*16 + (lane>>4)*4 + r] = acc[et][r];
}

// ---------------- state scan: one thread per (bh, e*64+d), coalesced ----------------
__global__ __launch_bounds__(256) void scan_ker(const float* __restrict__ kvb,
    const float* __restrict__ Bb, ushort_t* __restrict__ Sb){
  int gidx = blockIdx.x*256 + threadIdx.x;
  int bh = gidx >> 12; int f = gidx & 4095;
  float S = 0.f;
  const float* kp = &kvb[(size_t)bh*NCHK*4096 + f];
  ushort_t* sp = &Sb[(size_t)bh*NCHK*4096 + f];
  for (int n=0;n<NCHK;++n){
    sp[(size_t)n*4096] = f2bf(S);
    S = __expf(Bb[bh*NCHK+n])*S + kp[(size_t)n*4096];
  }
}

// ---------------- attention phase 3 (MFMA): intra + cross + rmsnorm + silu ----------------
__global__ __launch_bounds__(512,2) void attn_p3(const ushort_t* __restrict__ qkvg,
    const float* __restrict__ gtb, const ushort_t* __restrict__ Sb,
    ushort_t* __restrict__ oact){
  __shared__ __align__(16) ushort_t sh[(32768+16384+1024+32)/2];
  ushort_t* vt = sh;
  ushort_t* ps = sh + 16384;
  float* bcs = (float*)(sh + 24576);
  float* tmp = (float*)(sh + 25088);
  int bid = blockIdx.x; int n = bid&31; int bh = bid>>5; int b = bh>>4; int h = bh&15;
  int t0 = n*CHK; int tid = threadIdx.x; int lane = tid&63; int w = tid>>6;
  float vscan = 0.f;
  if (tid < 256){
    vscan = gtb[(size_t)bh*T_SEQ + t0 + tid];
    #pragma unroll
    for (int off=1; off<64; off<<=1){ float u = __shfl_up(vscan, off); if (lane>=off) vscan += u; }
    if (lane==63) tmp[w] = vscan;
  }
  __syncthreads();
  if (tid < 256){
    float pre=0;
    #pragma unroll
    for (int i=0;i<4;++i) if (i<w) pre += tmp[i];
    bcs[tid] = vscan + pre;
  }
  {
    int j = tid>>1, ehalf = tid&1;
    size_t rowb = ((size_t)(b*T_SEQ + t0 + j))*4096;
    #pragma unroll
    for (int q8=0; q8<4; ++q8){
      short8 v8 = *(const short8*)&qkvg[rowb + 2048 + h*HD + ehalf*32 + q8*8];
      #pragma unroll
      for (int kk=0; kk<8; ++kk){
        int e = ehalf*32 + q8*8 + kk;
        vt[(e<<8) + (((j>>3)^(e&7))<<3) + (j&7)] = (ushort_t)v8[kk];
      }
    }
  }
  __syncthreads();
  int wrow = w*32;
  size_t chunkbase = (size_t)b*T_SEQ + t0;
  bf16x8 qf[2][2];
  #pragma unroll
  for (int rt=0; rt<2; ++rt)
    #pragma unroll
    for (int s=0; s<2; ++s)
      qf[rt][s] = *(const bf16x8*)&qkvg[(chunkbase + wrow + rt*16 + (lane&15))*4096
                                        + h*HD + s*32 + (lane>>4)*8];
  f32x4 o_[2][4] = {};
  #pragma unroll
  for (int s=0; s<2; ++s)
    #pragma unroll
    for (int et=0; et<4; ++et){
      bf16x8 stf = *(const bf16x8*)&Sb[(size_t)bid*4096 + (et*16 + (lane&15))*64
                                       + s*32 + (lane>>4)*8];
      #pragma unroll
      for (int rt=0; rt<2; ++rt)
        o_[rt][et] = MFMA16(qf[rt][s], stf, o_[rt][et]);
    }
  #pragma unroll
  for (int rt=0; rt<2; ++rt)
    #pragma unroll
    for (int rr=0; rr<4; ++rr){
      float fs = 0.125f*__expf(bcs[wrow + rt*16 + (lane>>4)*4 + rr]);
      #pragma unroll
      for (int et=0; et<4; ++et) o_[rt][et][rr] *= fs;
    }
  for (int hb=0; hb<=w; ++hb){
    int jb = hb>>1, ch = hb&1;
    int jbase = jb*64 + ch*32;
    float mb = bcs[jb*64];
    float r8[2][4];
    #pragma unroll
    for (int rt=0; rt<2; ++rt)
      #pragma unroll
      for (int rr=0; rr<4; ++rr)
        r8[rt][rr] = 0.125f*__expf(bcs[wrow + rt*16 + (lane>>4)*4 + rr] - mb);
    float c2[2];
    #pragma unroll
    for (int ct=0; ct<2; ++ct)
      c2[ct] = __expf(mb - bcs[jbase + ct*16 + (lane&15)]);
    f32x4 s2[2][2] = {};
    #pragma unroll
    for (int s=0; s<2; ++s)
      #pragma unroll
      for (int ct=0; ct<2; ++ct){
        bf16x8 kf = *(const bf16x8*)&qkvg[(chunkbase + jbase + ct*16 + (lane&15))*4096
                                          + 1024 + h*HD + s*32 + (lane>>4)*8];
        #pragma unroll
        for (int rt=0; rt<2; ++rt)
          s2[rt][ct] = MFMA16(qf[rt][s], kf, s2[rt][ct]);
      }
    bool dia = (hb == w);
    #pragma unroll
    for (int rt=0; rt<2; ++rt)
      #pragma unroll
      for (int ct=0; ct<2; ++ct)
        #pragma unroll
        for (int rr=0; rr<4; ++rr){
          int pi = rt*16 + (lane>>4)*4 + rr;
          int pj = ct*16 + (lane&15);
          float pv = s2[rt][ct][rr] * r8[rt][rr] * c2[ct];
          if (dia && (jbase + pj) > (wrow + pi)) pv = 0.f;
          ps[w*1024 + pi*32 + (((pj>>3) ^ ((pi>>2)&3))<<3) + (pj&7)] = f2bf(pv);
        }
    bf16x8 vf[4];
    #pragma unroll
    for (int et=0; et<4; ++et){
      int e = et*16 + (lane&15);
      int jj = jbase + (lane>>4)*8;
      vf[et] = *(const bf16x8*)&vt[(e<<8) + (((jj>>3) ^ (e&7))<<3)];
    }
    bf16x8 pf[2];
    #pragma unroll
    for (int rt=0; rt<2; ++rt){
      int i = rt*16 + (lane&15);
      pf[rt] = *(const bf16x8*)&ps[w*1024 + i*32 + (((lane>>4) ^ ((i>>2)&3))<<3)];
    }
    #pragma unroll
    for (int rt=0; rt<2; ++rt)
      #pragma unroll
      for (int et=0; et<4; ++et)
        o_[rt][et] = MFMA16(pf[rt], vf[et], o_[rt][et]);
  }
  float rms8[2][4];
  #pragma unroll
  for (int rt=0; rt<2; ++rt)
    #pragma unroll
    for (int rr=0; rr<4; ++rr){
      float ssq = 0.f;
      #pragma unroll
      for (int et=0; et<4; ++et){ float xx = o_[rt][et][rr]; ssq += xx*xx; }
      ssq += __shfl_xor(ssq,1); ssq += __shfl_xor(ssq,2);
      ssq += __shfl_xor(ssq,4); ssq += __shfl_xor(ssq,8);
      rms8[rt][rr] = rsqrtf(ssq*(1.f/64.f)+1e-6f);
    }
  #pragma unroll
  for (int eh=0; eh<2; ++eh){
    #pragma unroll
    for (int rt=0; rt<2; ++rt)
      #pragma unroll
      for (int e2=0; e2<2; ++e2){
        int et = eh*2 + e2;
        #pragma unroll
        for (int rr=0; rr<4; ++rr){
          int pi = rt*16 + (lane>>4)*4 + rr;
          int pj = e2*16 + (lane&15);
          ps[w*1024 + pi*32 + (((pj>>3) ^ ((pi>>2)&3))<<3) + (pj&7)] =
            f2bf(o_[rt][et][rr]*rms8[rt][rr]);
        }
      }
    int i2 = lane&31, e16 = (lane>>5)*16;
    int gr0 = e16>>3;
    int f = (i2>>2)&3;
    short8 ov0 = *(const short8*)&ps[w*1024 + i2*32 + ((gr0^f)<<3)];
    short8 ov1 = *(const short8*)&ps[w*1024 + i2*32 + (((gr0+1)^f)<<3)];
    size_t rowg = chunkbase + wrow + i2;
    short8 gv0 = *(const short8*)&qkvg[rowg*4096 + 3072 + h*HD + eh*32 + e16];
    short8 gv1 = *(const short8*)&qkvg[rowg*4096 + 3072 + h*HD + eh*32 + e16 + 8];
    ushort_t outv[16];
    #pragma unroll
    for (int k=0;k<8;++k){
      float gf = bf2f((ushort_t)gv0[k]);
      float sg = gf/(1.f+__expf(-gf));
      outv[k] = f2bf(bf2f((ushort_t)ov0[k])*sg);
    }
    #pragma unroll
    for (int k=0;k<8;++k){
      float gf = bf2f((ushort_t)gv1[k]);
      float sg = gf/(1.f+__expf(-gf));
      outv[8+k] = f2bf(bf2f((ushort_t)ov1[k])*sg);
    }
    ushort_t* op = &oact[rowg*DIM + h*HD + eh*32 + e16];
    *(short8*)&op[0] = *(short8*)&outv[0];
    *(short8*)&op[8] = *(short8*)&outv[8];
  }
}

// ---------------- launch ----------------
extern "C" void kernel_launch(void* const* d_in, const int* in_sizes, int n_in,
                              void* d_out, int out_size, void* d_ws, size_t ws_size,
                              hipStream_t stream){
  const float* x  = (const float*)d_in[0];
  const float* Wq = (const float*)d_in[1];
  const float* Wk = (const float*)d_in[2];
  const float* Wv = (const float*)d_in[3];
  const float* Wg = (const float*)d_in[4];
  const float* Wgt= (const float*)d_in[5];
  const float* Wo = (const float*)d_in[6];
  float* out = (float*)d_out;

  char* p = (char*)d_ws;
  ushort_t* xbf  = (ushort_t*)p; p += (size_t)ROWS*DIM*2;
  ushort_t* wcat = (ushort_t*)p; p += (size_t)4*DIM*DIM*2;
  ushort_t* wot  = (ushort_t*)p; p += (size_t)DIM*DIM*2;
  ushort_t* qkvg = (ushort_t*)p; p += (size_t)ROWS*4096*2;
  float* gtb = (float*)p; p += (size_t)32*T_SEQ*4;
  float* Bb  = (float*)p; p += 1024*4;
  float* kvb = (float*)p; p += (size_t)1024*4096*4;
  ushort_t* Sb = (ushort_t*)p; p += (size_t)1024*4096*2;
  ushort_t* oact = (ushort_t*)p; p += (size_t)ROWS*DIM*2;
  if ((size_t)(p - (char*)d_ws) > ws_size) return;

  gt_ker<<<ROWS,256,0,stream>>>(x, Wgt, gtb, xbf);
  transpose_all<<<dim3(16,16,5),256,0,stream>>>(Wq, Wk, Wv, Wg, Wo, wcat, wot);
  gemm256<1><<<dim3(64*16), 512, 0, stream>>>(xbf, wcat, qkvg, 4096);
  rmsnorm_qkv<<<ROWS,256,0,stream>>>(qkvg);
  attn_p1<<<1024,256,0,stream>>>(qkvg, gtb, Bb, kvb);
  scan_ker<<<512,256,0,stream>>>(kvb, Bb, Sb);
  attn_p3<<<1024,512,0,stream>>>(qkvg, gtb, Sb, oact);
  gemm256<0><<<dim3(64*4), 512, 0, stream>>>(oact, wot, out, 1024);
}

// Round 5
// 426.070 us; speedup vs baseline: 1.0697x; 1.0171x over previous
//
#include <hip/hip_runtime.h>

#define T_SEQ 8192
#define NH 16
#define HD 64
#define DIM 1024
#define ROWS 16384   // 2*8192
#define CHK 256
#define NCHK 32

typedef float f32x4 __attribute__((ext_vector_type(4)));
typedef __bf16 bf16x8 __attribute__((ext_vector_type(8)));
typedef short short8 __attribute__((ext_vector_type(8)));
typedef short short4v __attribute__((ext_vector_type(4)));
typedef unsigned short ushort_t;

__device__ __forceinline__ float bf2f(ushort_t u){ return __uint_as_float(((unsigned)u)<<16); }
__device__ __forceinline__ ushort_t f2bf(float f){
  unsigned u = __float_as_uint(f);
  u += 0x7FFFu + ((u>>16)&1u);
  return (ushort_t)(u>>16);
}
#define BFLO(u) __uint_as_float((u)<<16)
#define BFHI(u) __uint_as_float((u)&0xFFFF0000u)
#define MFMA16(a,b,c) __builtin_amdgcn_mfma_f32_16x16x32_bf16((a),(b),(c),0,0,0)

__device__ __forceinline__ void gload16(const void* g, void* l){
  __builtin_amdgcn_global_load_lds(
      (const __attribute__((address_space(1))) void*)g,
      (__attribute__((address_space(3))) void*)l, 16, 0, 0);
}

// ---------------- transpose 5 weights 1024x1024 fp32 -> bf16 (N-major) ----------------
__global__ __launch_bounds__(256) void transpose_all(const float* __restrict__ Wq,
    const float* __restrict__ Wk, const float* __restrict__ Wv,
    const float* __restrict__ Wg, const float* __restrict__ Wo,
    ushort_t* __restrict__ wcat, ushort_t* __restrict__ wot){
  int z = blockIdx.z;
  const float* W = (z==0)?Wq:(z==1)?Wk:(z==2)?Wv:(z==3)?Wg:Wo;
  ushort_t* D = (z<4)? (wcat + (size_t)z*DIM*DIM) : wot;
  __shared__ float tile[64][65];
  int k0 = blockIdx.x*64, n0 = blockIdx.y*64;
  int tid = threadIdx.x;
  #pragma unroll
  for (int it=0; it<16; ++it){
    int idx = tid + it*256;
    int r = idx>>6, c = idx&63;
    tile[r][c] = W[(size_t)(k0+r)*DIM + n0+c];
  }
  __syncthreads();
  #pragma unroll
  for (int it=0; it<16; ++it){
    int idx = tid + it*256;
    int r = idx>>6, c = idx&63;
    D[(size_t)(n0+r)*DIM + k0+c] = f2bf(tile[c][r]);
  }
}

// ---------------- 256x256 MFMA GEMM, BK=64, dbuf 128KB LDS, COUNTED vmcnt ----------------
// 8 waves (2Mx4N), per-wave 128x64 out. Each wave issues 8 gload_lds per K-tile.
// Steady state: issue t+1's 8 -> vmcnt(8) (tile t landed, t+1 in flight) -> barrier
// -> 4 MFMA phases -> barrier. Never drains to 0 mid-loop (T4).
template<int OUT_BF16>
__global__ __launch_bounds__(512,2) void gemm256(const ushort_t* __restrict__ A,
    const ushort_t* __restrict__ Bt, void* __restrict__ Cv, int N){
  __shared__ __align__(16) ushort_t As[2*256*64];
  __shared__ __align__(16) ushort_t Bs[2*256*64];
  int tid = threadIdx.x, lane = tid&63, w = tid>>6;
  int wr = w>>2, wc = w&3;
  int nwg = gridDim.x, bid = blockIdx.x;
  int wg = (bid&7)*(nwg>>3) + (bid>>3);          // bijective XCD swizzle (nwg%8==0)
  int mb = wg & 63, nb = wg >> 6;                // M/256 == 64 for both GEMMs
  int m0 = mb<<8, n0 = nb<<8;
  const ushort_t* srcA = &A [(size_t)(m0 + w*32 + (lane>>3))*1024 + (((lane&7)^(lane>>3))<<3)];
  const ushort_t* srcB = &Bt[(size_t)(n0 + w*32 + (lane>>3))*1024 + (((lane&7)^(lane>>3))<<3)];
  int dstw = w*2048;
  f32x4 acc[8][4] = {};
  // prologue: issue K-tile 0 into buf0 (8 loads/wave), no wait yet
  #pragma unroll
  for (int q=0;q<4;++q) gload16(srcA + q*8192, &As[dstw + q*512]);
  #pragma unroll
  for (int q=0;q<4;++q) gload16(srcB + q*8192, &Bs[dstw + q*512]);

  const int NT = 16;                              // K=1024 / BK=64
  for (int t=0; t<NT; ++t){
    int db = t&1;
    const ushort_t* as = &As[db*16384];
    const ushort_t* bs = &Bs[db*16384];
    // issue K-tile t+1 into the other buffer (safe: its readers finished at the
    // end-of-compute barrier of iteration t-1), then wait ONLY for tile t.
    if (t+1 < NT){
      int xb = (db^1)*16384;
      #pragma unroll
      for (int q=0;q<4;++q) gload16(srcA + q*8192 + (t+1)*64, &As[xb + dstw + q*512]);
      #pragma unroll
      for (int q=0;q<4;++q) gload16(srcB + q*8192 + (t+1)*64, &Bs[xb + dstw + q*512]);
      asm volatile("s_waitcnt vmcnt(8)" ::: "memory");
    } else {
      asm volatile("s_waitcnt vmcnt(0)" ::: "memory");
    }
    __builtin_amdgcn_s_barrier();
    // B fragments for the whole K-tile (reused by all 4 phases)
    bf16x8 bfr[4][2];
    #pragma unroll
    for (int ni=0;ni<4;++ni){
      int row = wc*64 + ni*16 + (lane&15);
      #pragma unroll
      for (int kk=0;kk<2;++kk){
        int g = kk*4 + (lane>>4);
        bfr[ni][kk] = *(const bf16x8*)&bs[row*64 + ((g^(row&7))<<3)];
      }
    }
    // 4 phases x 16 MFMA, setprio around MFMA clusters
    #pragma unroll
    for (int p=0;p<4;++p){
      bf16x8 af[2][2];
      #pragma unroll
      for (int mi2=0;mi2<2;++mi2){
        int row = wr*128 + (p*2+mi2)*16 + (lane&15);
        #pragma unroll
        for (int kk=0;kk<2;++kk){
          int g = kk*4 + (lane>>4);
          af[mi2][kk] = *(const bf16x8*)&as[row*64 + ((g^(row&7))<<3)];
        }
      }
      __builtin_amdgcn_s_barrier();
      __builtin_amdgcn_s_setprio(1);
      #pragma unroll
      for (int mi2=0;mi2<2;++mi2)
        #pragma unroll
        for (int ni=0;ni<4;++ni)
          #pragma unroll
          for (int kk=0;kk<2;++kk)
            acc[p*2+mi2][ni] = MFMA16(af[mi2][kk], bfr[ni][kk], acc[p*2+mi2][ni]);
      __builtin_amdgcn_s_setprio(0);
    }
    __builtin_amdgcn_s_barrier();   // all reads of buf[t&1] done; t+2 may overwrite it
  }
  // epilogue
  #pragma unroll
  for (int m=0;m<8;++m){
    int row = m0 + wr*128 + m*16 + (lane>>4)*4;
    #pragma unroll
    for (int n=0;n<4;++n){
      int col = n0 + wc*64 + n*16 + (lane&15);
      #pragma unroll
      for (int r=0;r<4;++r){
        float v = acc[m][n][r];
        if (OUT_BF16) ((ushort_t*)Cv)[(size_t)(row+r)*N + col] = f2bf(v);
        else          ((float*)Cv)[(size_t)(row+r)*N + col] = v;
      }
    }
  }
}

// ---------------- rmsnorm of q,k,v rows (in place, bf16) ----------------
__global__ __launch_bounds__(256) void rmsnorm_qkv(ushort_t* __restrict__ qkvg){
  int row = blockIdx.x; int tid = threadIdx.x;
  size_t base = (size_t)row*4096;
  __shared__ float red[4];
  int lane = tid&63, w = tid>>6;
  for (int mat=0; mat<3; ++mat){
    ushort_t* pp = &qkvg[base + mat*1024 + tid*4];
    short4v sv = *(const short4v*)pp;
    float v0 = bf2f((ushort_t)sv[0]), v1 = bf2f((ushort_t)sv[1]);
    float v2 = bf2f((ushort_t)sv[2]), v3 = bf2f((ushort_t)sv[3]);
    float ss = v0*v0+v1*v1+v2*v2+v3*v3;
    #pragma unroll
    for (int off=32; off>=1; off>>=1) ss += __shfl_xor(ss, off);
    if (lane==0) red[w] = ss;
    __syncthreads();
    float tot = red[0]+red[1]+red[2]+red[3];
    float rms = rsqrtf(tot*(1.f/1024.f)+1e-6f);
    short4v ov;
    ov[0]=(short)f2bf(v0*rms); ov[1]=(short)f2bf(v1*rms);
    ov[2]=(short)f2bf(v2*rms); ov[3]=(short)f2bf(v3*rms);
    *(short4v*)pp = ov;
    __syncthreads();
  }
}

// ---------------- gt = logsigmoid(x @ Wgt)/16  +  fused x->bf16 cast ----------------
__global__ __launch_bounds__(256) void gt_ker(const float* __restrict__ x,
    const float* __restrict__ Wgt, float* __restrict__ gtb, ushort_t* __restrict__ xbf){
  int row = blockIdx.x; int b = row>>13; int t = row & (T_SEQ-1);
  int tid = threadIdx.x; int lane = tid&63; int w = tid>>6;
  __shared__ float xs[1024];
  #pragma unroll
  for (int i=0;i<4;++i) xs[tid+256*i] = x[(size_t)row*DIM + tid+256*i];
  __syncthreads();
  short4v xb4;
  #pragma unroll
  for (int k2=0;k2<4;++k2) xb4[k2] = (short)f2bf(xs[tid*4+k2]);
  *(short4v*)&xbf[(size_t)row*DIM + tid*4] = xb4;
  float a0=0,a1=0,a2=0,a3=0;
  #pragma unroll
  for (int jj=0;jj<16;++jj){
    int j = lane + 64*jj;
    float xv = xs[j];
    const float* wp = &Wgt[(size_t)j*NH + w*4];
    a0 += xv*wp[0]; a1 += xv*wp[1]; a2 += xv*wp[2]; a3 += xv*wp[3];
  }
  #pragma unroll
  for (int off=32; off>=1; off>>=1){
    a0 += __shfl_xor(a0, off); a1 += __shfl_xor(a1, off);
    a2 += __shfl_xor(a2, off); a3 += __shfl_xor(a3, off);
  }
  if (lane==0){
    float za[4] = {a0,a1,a2,a3};
    #pragma unroll
    for (int i=0;i<4;++i){
      float z = za[i];
      float ls = fminf(z,0.f) - log1pf(__expf(-fabsf(z)));
      gtb[((size_t)(b*NH + w*4 + i))*T_SEQ + t] = ls * (1.f/16.f);
    }
  }
}

// ---------------- attention phase 1 (MFMA): kv = kd^T v  (kv stored transposed [e][d]) ----------------
__global__ __launch_bounds__(256,2) void attn_p1(const ushort_t* __restrict__ qkvg,
    const float* __restrict__ gtb, float* __restrict__ Bb, float* __restrict__ kvb){
  __shared__ __align__(16) ushort_t sh2[32768];
  ushort_t* kdt = sh2;
  ushort_t* vt  = sh2 + 16384;
  float* tmp = (float*)sh2;
  int bid = blockIdx.x; int n = bid&31; int bh = bid>>5; int b = bh>>4; int h = bh&15;
  int t0 = n*CHK; int tid = threadIdx.x; int lane = tid&63; int w = tid>>6;
  float vscan = gtb[(size_t)bh*T_SEQ + t0 + tid];
  #pragma unroll
  for (int off=1; off<64; off<<=1){ float u = __shfl_up(vscan, off); if (lane>=off) vscan += u; }
  if (lane==63) tmp[w] = vscan;
  __syncthreads();
  float pre=0;
  #pragma unroll
  for (int i=0;i<4;++i) if (i<w) pre += tmp[i];
  float bc = vscan + pre;
  float Bn = tmp[0]+tmp[1]+tmp[2]+tmp[3];
  if (tid==0) Bb[bid] = Bn;
  __syncthreads();
  {
    int j = tid;
    size_t rowb = ((size_t)(b*T_SEQ + t0 + j))*4096;
    float sj = __expf(Bn - bc);
    #pragma unroll
    for (int q8=0; q8<8; ++q8){
      short8 k8 = *(const short8*)&qkvg[rowb + 1024 + h*HD + q8*8];
      short8 v8 = *(const short8*)&qkvg[rowb + 2048 + h*HD + q8*8];
      #pragma unroll
      for (int kk=0; kk<8; ++kk){
        int d = q8*8 + kk;
        kdt[(d<<8) + (((j>>3)^(d&7))<<3) + (j&7)] = f2bf(bf2f((ushort_t)k8[kk])*sj);
        vt [(d<<8) + (((j>>3)^(d&7))<<3) + (j&7)] = (ushort_t)v8[kk];
      }
    }
  }
  __syncthreads();
  f32x4 acc[4] = {};
  #pragma unroll
  for (int s=0; s<8; ++s){
    int d = w*16 + (lane&15);
    int jj = s*32 + (lane>>4)*8;
    bf16x8 ka = *(const bf16x8*)&kdt[(d<<8) + (((jj>>3)^(d&7))<<3)];
    #pragma unroll
    for (int et=0; et<4; ++et){
      int e = et*16 + (lane&15);
      bf16x8 vf = *(const bf16x8*)&vt[(e<<8) + (((jj>>3)^(e&7))<<3)];
      acc[et] = MFMA16(ka, vf, acc[et]);
    }
  }
  float* kvp = &kvb[(size_t)bid*4096];
  #pragma unroll
  for (int et=0; et<4; ++et)
    #pragma unroll
    for (int r=0; r<4; ++r)
      kvp[(et*16 + (lane&15))*64 + w*16 + (lane>>4)*4 + r] = acc[et][r];
}

// ---------------- state scan: one thread per (bh, e*64+d), coalesced ----------------
__global__ __launch_bounds__(256) void scan_ker(const float* __restrict__ kvb,
    const float* __restrict__ Bb, ushort_t* __restrict__ Sb){
  int gidx = blockIdx.x*256 + threadIdx.x;
  int bh = gidx >> 12; int f = gidx & 4095;
  float S = 0.f;
  const float* kp = &kvb[(size_t)bh*NCHK*4096 + f];
  ushort_t* sp = &Sb[(size_t)bh*NCHK*4096 + f];
  for (int n=0;n<NCHK;++n){
    sp[(size_t)n*4096] = f2bf(S);
    S = __expf(Bb[bh*NCHK+n])*S + kp[(size_t)n*4096];
  }
}

// ---------------- attention phase 3 (MFMA): intra + cross + rmsnorm + silu ----------------
__global__ __launch_bounds__(512,2) void attn_p3(const ushort_t* __restrict__ qkvg,
    const float* __restrict__ gtb, const ushort_t* __restrict__ Sb,
    ushort_t* __restrict__ oact){
  __shared__ __align__(16) ushort_t sh[(32768+16384+1024+32)/2];
  ushort_t* vt = sh;
  ushort_t* ps = sh + 16384;
  float* bcs = (float*)(sh + 24576);
  float* tmp = (float*)(sh + 25088);
  int bid = blockIdx.x; int n = bid&31; int bh = bid>>5; int b = bh>>4; int h = bh&15;
  int t0 = n*CHK; int tid = threadIdx.x; int lane = tid&63; int w = tid>>6;
  float vscan = 0.f;
  if (tid < 256){
    vscan = gtb[(size_t)bh*T_SEQ + t0 + tid];
    #pragma unroll
    for (int off=1; off<64; off<<=1){ float u = __shfl_up(vscan, off); if (lane>=off) vscan += u; }
    if (lane==63) tmp[w] = vscan;
  }
  __syncthreads();
  if (tid < 256){
    float pre=0;
    #pragma unroll
    for (int i=0;i<4;++i) if (i<w) pre += tmp[i];
    bcs[tid] = vscan + pre;
  }
  {
    int j = tid>>1, ehalf = tid&1;
    size_t rowb = ((size_t)(b*T_SEQ + t0 + j))*4096;
    #pragma unroll
    for (int q8=0; q8<4; ++q8){
      short8 v8 = *(const short8*)&qkvg[rowb + 2048 + h*HD + ehalf*32 + q8*8];
      #pragma unroll
      for (int kk=0; kk<8; ++kk){
        int e = ehalf*32 + q8*8 + kk;
        vt[(e<<8) + (((j>>3)^(e&7))<<3) + (j&7)] = (ushort_t)v8[kk];
      }
    }
  }
  __syncthreads();
  int wrow = w*32;
  size_t chunkbase = (size_t)b*T_SEQ + t0;
  bf16x8 qf[2][2];
  #pragma unroll
  for (int rt=0; rt<2; ++rt)
    #pragma unroll
    for (int s=0; s<2; ++s)
      qf[rt][s] = *(const bf16x8*)&qkvg[(chunkbase + wrow + rt*16 + (lane&15))*4096
                                        + h*HD + s*32 + (lane>>4)*8];
  f32x4 o_[2][4] = {};
  #pragma unroll
  for (int s=0; s<2; ++s)
    #pragma unroll
    for (int et=0; et<4; ++et){
      bf16x8 stf = *(const bf16x8*)&Sb[(size_t)bid*4096 + (et*16 + (lane&15))*64
                                       + s*32 + (lane>>4)*8];
      #pragma unroll
      for (int rt=0; rt<2; ++rt)
        o_[rt][et] = MFMA16(qf[rt][s], stf, o_[rt][et]);
    }
  #pragma unroll
  for (int rt=0; rt<2; ++rt)
    #pragma unroll
    for (int rr=0; rr<4; ++rr){
      float fs = 0.125f*__expf(bcs[wrow + rt*16 + (lane>>4)*4 + rr]);
      #pragma unroll
      for (int et=0; et<4; ++et) o_[rt][et][rr] *= fs;
    }
  for (int hb=0; hb<=w; ++hb){
    int jb = hb>>1, ch = hb&1;
    int jbase = jb*64 + ch*32;
    float mb = bcs[jb*64];
    float r8[2][4];
    #pragma unroll
    for (int rt=0; rt<2; ++rt)
      #pragma unroll
      for (int rr=0; rr<4; ++rr)
        r8[rt][rr] = 0.125f*__expf(bcs[wrow + rt*16 + (lane>>4)*4 + rr] - mb);
    float c2[2];
    #pragma unroll
    for (int ct=0; ct<2; ++ct)
      c2[ct] = __expf(mb - bcs[jbase + ct*16 + (lane&15)]);
    f32x4 s2[2][2] = {};
    #pragma unroll
    for (int s=0; s<2; ++s)
      #pragma unroll
      for (int ct=0; ct<2; ++ct){
        bf16x8 kf = *(const bf16x8*)&qkvg[(chunkbase + jbase + ct*16 + (lane&15))*4096
                                          + 1024 + h*HD + s*32 + (lane>>4)*8];
        #pragma unroll
        for (int rt=0; rt<2; ++rt)
          s2[rt][ct] = MFMA16(qf[rt][s], kf, s2[rt][ct]);
      }
    bool dia = (hb == w);
    #pragma unroll
    for (int rt=0; rt<2; ++rt)
      #pragma unroll
      for (int ct=0; ct<2; ++ct)
        #pragma unroll
        for (int rr=0; rr<4; ++rr){
          int pi = rt*16 + (lane>>4)*4 + rr;
          int pj = ct*16 + (lane&15);
          float pv = s2[rt][ct][rr] * r8[rt][rr] * c2[ct];
          if (dia && (jbase + pj) > (wrow + pi)) pv = 0.f;
          ps[w*1024 + pi*32 + (((pj>>3) ^ ((pi>>2)&3))<<3) + (pj&7)] = f2bf(pv);
        }
    bf16x8 vf[4];
    #pragma unroll
    for (int et=0; et<4; ++et){
      int e = et*16 + (lane&15);
      int jj = jbase + (lane>>4)*8;
      vf[et] = *(const bf16x8*)&vt[(e<<8) + (((jj>>3) ^ (e&7))<<3)];
    }
    bf16x8 pf[2];
    #pragma unroll
    for (int rt=0; rt<2; ++rt){
      int i = rt*16 + (lane&15);
      pf[rt] = *(const bf16x8*)&ps[w*1024 + i*32 + (((lane>>4) ^ ((i>>2)&3))<<3)];
    }
    #pragma unroll
    for (int rt=0; rt<2; ++rt)
      #pragma unroll
      for (int et=0; et<4; ++et)
        o_[rt][et] = MFMA16(pf[rt], vf[et], o_[rt][et]);
  }
  float rms8[2][4];
  #pragma unroll
  for (int rt=0; rt<2; ++rt)
    #pragma unroll
    for (int rr=0; rr<4; ++rr){
      float ssq = 0.f;
      #pragma unroll
      for (int et=0; et<4; ++et){ float xx = o_[rt][et][rr]; ssq += xx*xx; }
      ssq += __shfl_xor(ssq,1); ssq += __shfl_xor(ssq,2);
      ssq += __shfl_xor(ssq,4); ssq += __shfl_xor(ssq,8);
      rms8[rt][rr] = rsqrtf(ssq*(1.f/64.f)+1e-6f);
    }
  #pragma unroll
  for (int eh=0; eh<2; ++eh){
    #pragma unroll
    for (int rt=0; rt<2; ++rt)
      #pragma unroll
      for (int e2=0; e2<2; ++e2){
        int et = eh*2 + e2;
        #pragma unroll
        for (int rr=0; rr<4; ++rr){
          int pi = rt*16 + (lane>>4)*4 + rr;
          int pj = e2*16 + (lane&15);
          ps[w*1024 + pi*32 + (((pj>>3) ^ ((pi>>2)&3))<<3) + (pj&7)] =
            f2bf(o_[rt][et][rr]*rms8[rt][rr]);
        }
      }
    int i2 = lane&31, e16 = (lane>>5)*16;
    int gr0 = e16>>3;
    int f = (i2>>2)&3;
    short8 ov0 = *(const short8*)&ps[w*1024 + i2*32 + ((gr0^f)<<3)];
    short8 ov1 = *(const short8*)&ps[w*1024 + i2*32 + (((gr0+1)^f)<<3)];
    size_t rowg = chunkbase + wrow + i2;
    short8 gv0 = *(const short8*)&qkvg[rowg*4096 + 3072 + h*HD + eh*32 + e16];
    short8 gv1 = *(const short8*)&qkvg[rowg*4096 + 3072 + h*HD + eh*32 + e16 + 8];
    ushort_t outv[16];
    #pragma unroll
    for (int k=0;k<8;++k){
      float gf = bf2f((ushort_t)gv0[k]);
      float sg = gf/(1.f+__expf(-gf));
      outv[k] = f2bf(bf2f((ushort_t)ov0[k])*sg);
    }
    #pragma unroll
    for (int k=0;k<8;++k){
      float gf = bf2f((ushort_t)gv1[k]);
      float sg = gf/(1.f+__expf(-gf));
      outv[8+k] = f2bf(bf2f((ushort_t)ov1[k])*sg);
    }
    ushort_t* op = &oact[rowg*DIM + h*HD + eh*32 + e16];
    *(short8*)&op[0] = *(short8*)&outv[0];
    *(short8*)&op[8] = *(short8*)&outv[8];
  }
}

// ---------------- launch ----------------
extern "C" void kernel_launch(void* const* d_in, const int* in_sizes, int n_in,
                              void* d_out, int out_size, void* d_ws, size_t ws_size,
                              hipStream_t stream){
  const float* x  = (const float*)d_in[0];
  const float* Wq = (const float*)d_in[1];
  const float* Wk = (const float*)d_in[2];
  const float* Wv = (const float*)d_in[3];
  const float* Wg = (const float*)d_in[4];
  const float* Wgt= (const float*)d_in[5];
  const float* Wo = (const float*)d_in[6];
  float* out = (float*)d_out;

  char* p = (char*)d_ws;
  ushort_t* xbf  = (ushort_t*)p; p += (size_t)ROWS*DIM*2;
  ushort_t* wcat = (ushort_t*)p; p += (size_t)4*DIM*DIM*2;
  ushort_t* wot  = (ushort_t*)p; p += (size_t)DIM*DIM*2;
  ushort_t* qkvg = (ushort_t*)p; p += (size_t)ROWS*4096*2;
  float* gtb = (float*)p; p += (size_t)32*T_SEQ*4;
  float* Bb  = (float*)p; p += 1024*4;
  float* kvb = (float*)p; p += (size_t)1024*4096*4;
  ushort_t* Sb = (ushort_t*)p; p += (size_t)1024*4096*2;
  ushort_t* oact = (ushort_t*)p; p += (size_t)ROWS*DIM*2;
  if ((size_t)(p - (char*)d_ws) > ws_size) return;

  gt_ker<<<ROWS,256,0,stream>>>(x, Wgt, gtb, xbf);
  transpose_all<<<dim3(16,16,5),256,0,stream>>>(Wq, Wk, Wv, Wg, Wo, wcat, wot);
  gemm256<1><<<dim3(64*16), 512, 0, stream>>>(xbf, wcat, qkvg, 4096);
  rmsnorm_qkv<<<ROWS,256,0,stream>>>(qkvg);
  attn_p1<<<1024,256,0,stream>>>(qkvg, gtb, Bb, kvb);
  scan_ker<<<512,256,0,stream>>>(kvb, Bb, Sb);
  attn_p3<<<1024,512,0,stream>>>(qkvg, gtb, Sb, oact);
  gemm256<0><<<dim3(64*4), 512, 0, stream>>>(oact, wot, out, 1024);
}

// Round 6
// 393.590 us; speedup vs baseline: 1.1579x; 1.0825x over previous
//
#include <hip/hip_runtime.h>

#define T_SEQ 8192
#define NH 16
#define HD 64
#define DIM 1024
#define ROWS 16384   // 2*8192
#define CHK 256
#define NCHK 32

typedef float f32x4 __attribute__((ext_vector_type(4)));
typedef __bf16 bf16x8 __attribute__((ext_vector_type(8)));
typedef short short8 __attribute__((ext_vector_type(8)));
typedef short short4v __attribute__((ext_vector_type(4)));
typedef unsigned short ushort_t;

__device__ __forceinline__ float bf2f(ushort_t u){ return __uint_as_float(((unsigned)u)<<16); }
__device__ __forceinline__ ushort_t f2bf(float f){
  unsigned u = __float_as_uint(f);
  u += 0x7FFFu + ((u>>16)&1u);
  return (ushort_t)(u>>16);
}
#define BFLO(u) __uint_as_float((u)<<16)
#define BFHI(u) __uint_as_float((u)&0xFFFF0000u)
#define MFMA16(a,b,c) __builtin_amdgcn_mfma_f32_16x16x32_bf16((a),(b),(c),0,0,0)

// ---------------- transpose 5 weights 1024x1024 fp32 -> bf16 (N-major) ----------------
__global__ __launch_bounds__(256) void transpose_all(const float* __restrict__ Wq,
    const float* __restrict__ Wk, const float* __restrict__ Wv,
    const float* __restrict__ Wg, const float* __restrict__ Wo,
    ushort_t* __restrict__ wcat, ushort_t* __restrict__ wot){
  int z = blockIdx.z;
  const float* W = (z==0)?Wq:(z==1)?Wk:(z==2)?Wv:(z==3)?Wg:Wo;
  ushort_t* D = (z<4)? (wcat + (size_t)z*DIM*DIM) : wot;
  __shared__ float tile[64][65];
  int k0 = blockIdx.x*64, n0 = blockIdx.y*64;
  int tid = threadIdx.x;
  #pragma unroll
  for (int it=0; it<16; ++it){
    int idx = tid + it*256;
    int r = idx>>6, c = idx&63;
    tile[r][c] = W[(size_t)(k0+r)*DIM + n0+c];
  }
  __syncthreads();
  #pragma unroll
  for (int it=0; it<16; ++it){
    int idx = tid + it*256;
    int r = idx>>6, c = idx&63;
    D[(size_t)(n0+r)*DIM + k0+c] = f2bf(tile[c][r]);
  }
}

// ---------------- MFMA GEMM (R2-proven, 910 TF): C[M,N] = A[M,K] * Bt[N,K]^T ----------------
// 128x128 tile, BK=64, 4 waves (2x2), XOR-swizzled LDS, reg staging.
// OUT_BF16 path additionally emits per-row sum-of-squares partials for q,k,v
// (blockIdx.y<24) into ssqp[slot][row], slot = blockIdx.y*2+wc. Deterministic:
// each (slot,row) written by exactly one wave of one block.
template<int OUT_BF16>
__global__ __launch_bounds__(256,2) void gemm_bt(const ushort_t* __restrict__ A,
    const ushort_t* __restrict__ Bt, void* __restrict__ Cv, int M, int N, int K,
    float* __restrict__ ssqp){
  __shared__ __align__(16) ushort_t As[128*64];
  __shared__ __align__(16) ushort_t Bs[128*64];
  int tid = threadIdx.x;
  int lane = tid & 63, wid = tid >> 6;
  int wr = wid >> 1, wc = wid & 1;
  int m0 = blockIdx.x * 128, n0 = blockIdx.y * 128;
  f32x4 acc[4][4] = {};
  int srow = tid >> 3;
  int sg = tid & 7;
  const int nkt = K >> 6;
  for (int kt = 0; kt < nkt; ++kt){
    short8 ra[4], rb[4];
    #pragma unroll
    for (int s = 0; s < 4; ++s){
      int row = s*32 + srow;
      int gl = sg ^ (row & 7);
      ra[s] = *(const short8*)&A[(size_t)(m0 + row)*K + kt*64 + gl*8];
      rb[s] = *(const short8*)&Bt[(size_t)(n0 + row)*K + kt*64 + gl*8];
    }
    __syncthreads();
    #pragma unroll
    for (int s = 0; s < 4; ++s){
      int row = s*32 + srow;
      *(short8*)&As[row*64 + sg*8] = ra[s];
      *(short8*)&Bs[row*64 + sg*8] = rb[s];
    }
    __syncthreads();
    #pragma unroll
    for (int kk = 0; kk < 2; ++kk){
      bf16x8 af[4], bfv[4];
      #pragma unroll
      for (int m = 0; m < 4; ++m){
        int row = wr*64 + m*16 + (lane & 15);
        int g = kk*4 + (lane >> 4);
        af[m] = *(const bf16x8*)&As[row*64 + ((g ^ (row & 7))<<3)];
      }
      #pragma unroll
      for (int n = 0; n < 4; ++n){
        int row = wc*64 + n*16 + (lane & 15);
        int g = kk*4 + (lane >> 4);
        bfv[n] = *(const bf16x8*)&Bs[row*64 + ((g ^ (row & 7))<<3)];
      }
      #pragma unroll
      for (int m = 0; m < 4; ++m)
        #pragma unroll
        for (int n = 0; n < 4; ++n)
          acc[m][n] = MFMA16(af[m], bfv[n], acc[m][n]);
    }
  }
  // epilogue: C write (+ ssq partials for q,k,v on the bf16 path)
  #pragma unroll
  for (int m = 0; m < 4; ++m){
    int row = m0 + wr*64 + m*16 + (lane>>4)*4;
    #pragma unroll
    for (int n = 0; n < 4; ++n){
      int col = n0 + wc*64 + n*16 + (lane & 15);
      #pragma unroll
      for (int r = 0; r < 4; ++r){
        float v = acc[m][n][r];
        if (OUT_BF16) ((ushort_t*)Cv)[(size_t)(row+r)*N + col] = f2bf(v);
        else          ((float*)Cv)[(size_t)(row+r)*N + col] = v;
      }
    }
  }
  if (OUT_BF16 && blockIdx.y < 24){
    int slot = blockIdx.y*2 + wc;
    #pragma unroll
    for (int m = 0; m < 4; ++m){
      #pragma unroll
      for (int r = 0; r < 4; ++r){
        float s = 0.f;
        #pragma unroll
        for (int n = 0; n < 4; ++n){ float xx = acc[m][n][r]; s += xx*xx; }
        s += __shfl_xor(s,1); s += __shfl_xor(s,2);
        s += __shfl_xor(s,4); s += __shfl_xor(s,8);
        if ((lane & 15) == 0){
          int row = m0 + wr*64 + m*16 + (lane>>4)*4 + r;
          ssqp[(size_t)slot*ROWS + row] = s;
        }
      }
    }
  }
}

// ---------------- combine ssq partials -> inverse rms per (mat,row) ----------------
__global__ __launch_bounds__(256) void rms_combine(const float* __restrict__ ssqp,
                                                   float* __restrict__ rmsb){
  int idx = blockIdx.x*256 + threadIdx.x;    // 3*16384
  int mat = idx >> 14, row = idx & (ROWS-1);
  float s = 0.f;
  #pragma unroll
  for (int k=0;k<16;++k) s += ssqp[(size_t)(mat*16+k)*ROWS + row];
  rmsb[idx] = rsqrtf(s*(1.f/1024.f)+1e-6f);
}

// ---------------- gt = logsigmoid(x @ Wgt)/16  +  fused x->bf16 cast ----------------
__global__ __launch_bounds__(256) void gt_ker(const float* __restrict__ x,
    const float* __restrict__ Wgt, float* __restrict__ gtb, ushort_t* __restrict__ xbf){
  int row = blockIdx.x; int b = row>>13; int t = row & (T_SEQ-1);
  int tid = threadIdx.x; int lane = tid&63; int w = tid>>6;
  __shared__ float xs[1024];
  #pragma unroll
  for (int i=0;i<4;++i) xs[tid+256*i] = x[(size_t)row*DIM + tid+256*i];
  __syncthreads();
  short4v xb4;
  #pragma unroll
  for (int k2=0;k2<4;++k2) xb4[k2] = (short)f2bf(xs[tid*4+k2]);
  *(short4v*)&xbf[(size_t)row*DIM + tid*4] = xb4;
  float a0=0,a1=0,a2=0,a3=0;
  #pragma unroll
  for (int jj=0;jj<16;++jj){
    int j = lane + 64*jj;
    float xv = xs[j];
    const float* wp = &Wgt[(size_t)j*NH + w*4];
    a0 += xv*wp[0]; a1 += xv*wp[1]; a2 += xv*wp[2]; a3 += xv*wp[3];
  }
  #pragma unroll
  for (int off=32; off>=1; off>>=1){
    a0 += __shfl_xor(a0, off); a1 += __shfl_xor(a1, off);
    a2 += __shfl_xor(a2, off); a3 += __shfl_xor(a3, off);
  }
  if (lane==0){
    float za[4] = {a0,a1,a2,a3};
    #pragma unroll
    for (int i=0;i<4;++i){
      float z = za[i];
      float ls = fminf(z,0.f) - log1pf(__expf(-fabsf(z)));
      gtb[((size_t)(b*NH + w*4 + i))*T_SEQ + t] = ls * (1.f/16.f);
    }
  }
}

// ---------------- attention phase 1 (MFMA): kv = (k*rms_k*dec)^T (v*rms_v) ----------------
__global__ __launch_bounds__(256,2) void attn_p1(const ushort_t* __restrict__ qkvg,
    const float* __restrict__ gtb, const float* __restrict__ rmsb,
    float* __restrict__ Bb, float* __restrict__ kvb){
  __shared__ __align__(16) ushort_t sh2[32768];
  ushort_t* kdt = sh2;
  ushort_t* vt  = sh2 + 16384;
  float* tmp = (float*)sh2;
  int bid = blockIdx.x; int n = bid&31; int bh = bid>>5; int b = bh>>4; int h = bh&15;
  int t0 = n*CHK; int tid = threadIdx.x; int lane = tid&63; int w = tid>>6;
  float vscan = gtb[(size_t)bh*T_SEQ + t0 + tid];
  #pragma unroll
  for (int off=1; off<64; off<<=1){ float u = __shfl_up(vscan, off); if (lane>=off) vscan += u; }
  if (lane==63) tmp[w] = vscan;
  __syncthreads();
  float pre=0;
  #pragma unroll
  for (int i=0;i<4;++i) if (i<w) pre += tmp[i];
  float bc = vscan + pre;
  float Bn = tmp[0]+tmp[1]+tmp[2]+tmp[3];
  if (tid==0) Bb[bid] = Bn;
  __syncthreads();
  {
    int j = tid;
    int grow = b*T_SEQ + t0 + j;
    size_t rowb = (size_t)grow*4096;
    float fk = rmsb[ROWS + grow] * __expf(Bn - bc);
    float fv = rmsb[2*ROWS + grow];
    #pragma unroll
    for (int q8=0; q8<8; ++q8){
      short8 k8 = *(const short8*)&qkvg[rowb + 1024 + h*HD + q8*8];
      short8 v8 = *(const short8*)&qkvg[rowb + 2048 + h*HD + q8*8];
      #pragma unroll
      for (int kk=0; kk<8; ++kk){
        int d = q8*8 + kk;
        kdt[(d<<8) + (((j>>3)^(d&7))<<3) + (j&7)] = f2bf(bf2f((ushort_t)k8[kk])*fk);
        vt [(d<<8) + (((j>>3)^(d&7))<<3) + (j&7)] = f2bf(bf2f((ushort_t)v8[kk])*fv);
      }
    }
  }
  __syncthreads();
  f32x4 acc[4] = {};
  #pragma unroll
  for (int s=0; s<8; ++s){
    int d = w*16 + (lane&15);
    int jj = s*32 + (lane>>4)*8;
    bf16x8 ka = *(const bf16x8*)&kdt[(d<<8) + (((jj>>3)^(d&7))<<3)];
    #pragma unroll
    for (int et=0; et<4; ++et){
      int e = et*16 + (lane&15);
      bf16x8 vf = *(const bf16x8*)&vt[(e<<8) + (((jj>>3)^(e&7))<<3)];
      acc[et] = MFMA16(ka, vf, acc[et]);
    }
  }
  float* kvp = &kvb[(size_t)bid*4096];
  #pragma unroll
  for (int et=0; et<4; ++et)
    #pragma unroll
    for (int r=0; r<4; ++r)
      kvp[(et*16 + (lane&15))*64 + w*16 + (lane>>4)*4 + r] = acc[et][r];
}

// ---------------- state scan: one thread per (bh, e*64+d), coalesced ----------------
__global__ __launch_bounds__(256) void scan_ker(const float* __restrict__ kvb,
    const float* __restrict__ Bb, ushort_t* __restrict__ Sb){
  int gidx = blockIdx.x*256 + threadIdx.x;
  int bh = gidx >> 12; int f = gidx & 4095;
  float S = 0.f;
  const float* kp = &kvb[(size_t)bh*NCHK*4096 + f];
  ushort_t* sp = &Sb[(size_t)bh*NCHK*4096 + f];
  for (int n=0;n<NCHK;++n){
    sp[(size_t)n*4096] = f2bf(S);
    S = __expf(Bb[bh*NCHK+n])*S + kp[(size_t)n*4096];
  }
}

// ---------------- attention phase 3 (MFMA): intra + cross + rmsnorm + silu ----------------
// rms factors folded: rms_q -> row factors (fs, r8), rms_k -> col factor (c2),
// rms_v -> vt staging.
__global__ __launch_bounds__(512,2) void attn_p3(const ushort_t* __restrict__ qkvg,
    const float* __restrict__ gtb, const float* __restrict__ rmsb,
    const ushort_t* __restrict__ Sb, ushort_t* __restrict__ oact){
  __shared__ __align__(16) ushort_t sh[(32768+16384+1024+32+2048)/2];
  ushort_t* vt = sh;                         // [e=64][j=256] swizzled
  ushort_t* ps = sh + 16384;                 // per-wave [32][32] swizzled
  float* bcs = (float*)(sh + 24576);
  float* tmp = (float*)(sh + 25088);
  float* rqs = (float*)(sh + 25104);         // 256 floats
  float* rks = (float*)(sh + 25616);         // 256 floats
  int bid = blockIdx.x; int n = bid&31; int bh = bid>>5; int b = bh>>4; int h = bh&15;
  int t0 = n*CHK; int tid = threadIdx.x; int lane = tid&63; int w = tid>>6;
  float vscan = 0.f;
  if (tid < 256){
    vscan = gtb[(size_t)bh*T_SEQ + t0 + tid];
    #pragma unroll
    for (int off=1; off<64; off<<=1){ float u = __shfl_up(vscan, off); if (lane>=off) vscan += u; }
    if (lane==63) tmp[w] = vscan;
  }
  __syncthreads();
  if (tid < 256){
    float pre=0;
    #pragma unroll
    for (int i=0;i<4;++i) if (i<w) pre += tmp[i];
    bcs[tid] = vscan + pre;
    int grow = b*T_SEQ + t0 + tid;
    rqs[tid] = rmsb[grow];
    rks[tid] = rmsb[ROWS + grow];
  }
  {
    int j = tid>>1, ehalf = tid&1;
    int grow = b*T_SEQ + t0 + j;
    size_t rowb = (size_t)grow*4096;
    float fv = rmsb[2*ROWS + grow];
    #pragma unroll
    for (int q8=0; q8<4; ++q8){
      short8 v8 = *(const short8*)&qkvg[rowb + 2048 + h*HD + ehalf*32 + q8*8];
      #pragma unroll
      for (int kk=0; kk<8; ++kk){
        int e = ehalf*32 + q8*8 + kk;
        vt[(e<<8) + (((j>>3)^(e&7))<<3) + (j&7)] = f2bf(bf2f((ushort_t)v8[kk])*fv);
      }
    }
  }
  __syncthreads();
  int wrow = w*32;
  size_t chunkbase = (size_t)b*T_SEQ + t0;
  bf16x8 qf[2][2];
  #pragma unroll
  for (int rt=0; rt<2; ++rt)
    #pragma unroll
    for (int s=0; s<2; ++s)
      qf[rt][s] = *(const bf16x8*)&qkvg[(chunkbase + wrow + rt*16 + (lane&15))*4096
                                        + h*HD + s*32 + (lane>>4)*8];
  f32x4 o_[2][4] = {};
  #pragma unroll
  for (int s=0; s<2; ++s)
    #pragma unroll
    for (int et=0; et<4; ++et){
      bf16x8 stf = *(const bf16x8*)&Sb[(size_t)bid*4096 + (et*16 + (lane&15))*64
                                       + s*32 + (lane>>4)*8];
      #pragma unroll
      for (int rt=0; rt<2; ++rt)
        o_[rt][et] = MFMA16(qf[rt][s], stf, o_[rt][et]);
    }
  #pragma unroll
  for (int rt=0; rt<2; ++rt)
    #pragma unroll
    for (int rr=0; rr<4; ++rr){
      int ri = wrow + rt*16 + (lane>>4)*4 + rr;
      float fs = 0.125f*__expf(bcs[ri])*rqs[ri];
      #pragma unroll
      for (int et=0; et<4; ++et) o_[rt][et][rr] *= fs;
    }
  for (int hb=0; hb<=w; ++hb){
    int jb = hb>>1, ch = hb&1;
    int jbase = jb*64 + ch*32;
    float mb = bcs[jb*64];
    float r8[2][4];
    #pragma unroll
    for (int rt=0; rt<2; ++rt)
      #pragma unroll
      for (int rr=0; rr<4; ++rr){
        int ri = wrow + rt*16 + (lane>>4)*4 + rr;
        r8[rt][rr] = 0.125f*__expf(bcs[ri] - mb)*rqs[ri];
      }
    float c2[2];
    #pragma unroll
    for (int ct=0; ct<2; ++ct){
      int jc = jbase + ct*16 + (lane&15);
      c2[ct] = __expf(mb - bcs[jc])*rks[jc];
    }
    f32x4 s2[2][2] = {};
    #pragma unroll
    for (int s=0; s<2; ++s)
      #pragma unroll
      for (int ct=0; ct<2; ++ct){
        bf16x8 kf = *(const bf16x8*)&qkvg[(chunkbase + jbase + ct*16 + (lane&15))*4096
                                          + 1024 + h*HD + s*32 + (lane>>4)*8];
        #pragma unroll
        for (int rt=0; rt<2; ++rt)
          s2[rt][ct] = MFMA16(qf[rt][s], kf, s2[rt][ct]);
      }
    bool dia = (hb == w);
    #pragma unroll
    for (int rt=0; rt<2; ++rt)
      #pragma unroll
      for (int ct=0; ct<2; ++ct)
        #pragma unroll
        for (int rr=0; rr<4; ++rr){
          int pi = rt*16 + (lane>>4)*4 + rr;
          int pj = ct*16 + (lane&15);
          float pv = s2[rt][ct][rr] * r8[rt][rr] * c2[ct];
          if (dia && (jbase + pj) > (wrow + pi)) pv = 0.f;
          ps[w*1024 + pi*32 + (((pj>>3) ^ ((pi>>2)&3))<<3) + (pj&7)] = f2bf(pv);
        }
    bf16x8 vf[4];
    #pragma unroll
    for (int et=0; et<4; ++et){
      int e = et*16 + (lane&15);
      int jj = jbase + (lane>>4)*8;
      vf[et] = *(const bf16x8*)&vt[(e<<8) + (((jj>>3) ^ (e&7))<<3)];
    }
    bf16x8 pf[2];
    #pragma unroll
    for (int rt=0; rt<2; ++rt){
      int i = rt*16 + (lane&15);
      pf[rt] = *(const bf16x8*)&ps[w*1024 + i*32 + (((lane>>4) ^ ((i>>2)&3))<<3)];
    }
    #pragma unroll
    for (int rt=0; rt<2; ++rt)
      #pragma unroll
      for (int et=0; et<4; ++et)
        o_[rt][et] = MFMA16(pf[rt], vf[et], o_[rt][et]);
  }
  float rms8[2][4];
  #pragma unroll
  for (int rt=0; rt<2; ++rt)
    #pragma unroll
    for (int rr=0; rr<4; ++rr){
      float ssq = 0.f;
      #pragma unroll
      for (int et=0; et<4; ++et){ float xx = o_[rt][et][rr]; ssq += xx*xx; }
      ssq += __shfl_xor(ssq,1); ssq += __shfl_xor(ssq,2);
      ssq += __shfl_xor(ssq,4); ssq += __shfl_xor(ssq,8);
      rms8[rt][rr] = rsqrtf(ssq*(1.f/64.f)+1e-6f);
    }
  #pragma unroll
  for (int eh=0; eh<2; ++eh){
    #pragma unroll
    for (int rt=0; rt<2; ++rt)
      #pragma unroll
      for (int e2=0; e2<2; ++e2){
        int et = eh*2 + e2;
        #pragma unroll
        for (int rr=0; rr<4; ++rr){
          int pi = rt*16 + (lane>>4)*4 + rr;
          int pj = e2*16 + (lane&15);
          ps[w*1024 + pi*32 + (((pj>>3) ^ ((pi>>2)&3))<<3) + (pj&7)] =
            f2bf(o_[rt][et][rr]*rms8[rt][rr]);
        }
      }
    int i2 = lane&31, e16 = (lane>>5)*16;
    int gr0 = e16>>3;
    int f = (i2>>2)&3;
    short8 ov0 = *(const short8*)&ps[w*1024 + i2*32 + ((gr0^f)<<3)];
    short8 ov1 = *(const short8*)&ps[w*1024 + i2*32 + (((gr0+1)^f)<<3)];
    size_t rowg = chunkbase + wrow + i2;
    short8 gv0 = *(const short8*)&qkvg[rowg*4096 + 3072 + h*HD + eh*32 + e16];
    short8 gv1 = *(const short8*)&qkvg[rowg*4096 + 3072 + h*HD + eh*32 + e16 + 8];
    ushort_t outv[16];
    #pragma unroll
    for (int k=0;k<8;++k){
      float gf = bf2f((ushort_t)gv0[k]);
      float sg = gf/(1.f+__expf(-gf));
      outv[k] = f2bf(bf2f((ushort_t)ov0[k])*sg);
    }
    #pragma unroll
    for (int k=0;k<8;++k){
      float gf = bf2f((ushort_t)gv1[k]);
      float sg = gf/(1.f+__expf(-gf));
      outv[8+k] = f2bf(bf2f((ushort_t)ov1[k])*sg);
    }
    ushort_t* op = &oact[rowg*DIM + h*HD + eh*32 + e16];
    *(short8*)&op[0] = *(short8*)&outv[0];
    *(short8*)&op[8] = *(short8*)&outv[8];
  }
}

// ---------------- launch ----------------
extern "C" void kernel_launch(void* const* d_in, const int* in_sizes, int n_in,
                              void* d_out, int out_size, void* d_ws, size_t ws_size,
                              hipStream_t stream){
  const float* x  = (const float*)d_in[0];
  const float* Wq = (const float*)d_in[1];
  const float* Wk = (const float*)d_in[2];
  const float* Wv = (const float*)d_in[3];
  const float* Wg = (const float*)d_in[4];
  const float* Wgt= (const float*)d_in[5];
  const float* Wo = (const float*)d_in[6];
  float* out = (float*)d_out;

  char* p = (char*)d_ws;
  ushort_t* xbf  = (ushort_t*)p; p += (size_t)ROWS*DIM*2;
  ushort_t* wcat = (ushort_t*)p; p += (size_t)4*DIM*DIM*2;
  ushort_t* wot  = (ushort_t*)p; p += (size_t)DIM*DIM*2;
  ushort_t* qkvg = (ushort_t*)p; p += (size_t)ROWS*4096*2;
  float* gtb = (float*)p; p += (size_t)32*T_SEQ*4;
  float* Bb  = (float*)p; p += 1024*4;
  float* kvb = (float*)p; p += (size_t)1024*4096*4;
  ushort_t* Sb = (ushort_t*)p; p += (size_t)1024*4096*2;
  ushort_t* oact = (ushort_t*)p; p += (size_t)ROWS*DIM*2;
  float* ssqp = (float*)p; p += (size_t)48*ROWS*4;
  float* rmsb = (float*)p; p += (size_t)3*ROWS*4;
  if ((size_t)(p - (char*)d_ws) > ws_size) return;

  gt_ker<<<ROWS,256,0,stream>>>(x, Wgt, gtb, xbf);
  transpose_all<<<dim3(16,16,5),256,0,stream>>>(Wq, Wk, Wv, Wg, Wo, wcat, wot);
  gemm_bt<1><<<dim3(ROWS/128, 4096/128), 256, 0, stream>>>(xbf, wcat, qkvg, ROWS, 4096, DIM, ssqp);
  rms_combine<<<(3*ROWS)/256,256,0,stream>>>(ssqp, rmsb);
  attn_p1<<<1024,256,0,stream>>>(qkvg, gtb, rmsb, Bb, kvb);
  scan_ker<<<512,256,0,stream>>>(kvb, Bb, Sb);
  attn_p3<<<1024,512,0,stream>>>(qkvg, gtb, rmsb, Sb, oact);
  gemm_bt<0><<<dim3(ROWS/128, 1024/128), 256, 0, stream>>>(oact, wot, out, ROWS, 1024, DIM, nullptr);
}